// Round 19
// baseline (992.470 us; speedup 1.0000x reference)
//
#include <hip/hip_runtime.h>
#include <stdint.h>
#include <stddef.h>

// SpatialNSA on MI355X — round 19:
//  * implicit unfold: the two K=4096 GEMMs read the (b,4096,256) K/V channel
//    fields directly (k_mgs_unf) with the K-dimension permuted to
//    j' = (kh*4+kw)*256 + ch (weights pre-permuted). Kills the 16x-redundant
//    94.5MB unfold matrix (round-18 top dispatch: 250MB fetch-bound).
//  * pos_embed folds into the w1 bias exactly: bias' = b1 + pos@W1 (k_posw1).
//  * k_unfold2 -> k_splitkv (channel split only).

#define DEV __device__ __forceinline__

typedef __attribute__((ext_vector_type(8))) short short8;
typedef __attribute__((ext_vector_type(4))) float f32x4;
typedef unsigned short u16;

DEV u16 f2bf(float f){
    unsigned u = __float_as_uint(f);
    u += 0x7FFFu + ((u>>16)&1u);   // RNE
    return (u16)(u>>16);
}
DEV float bf2f(u16 u){ return __uint_as_float(((unsigned)u)<<16); }

#define LGKM0() asm volatile("s_waitcnt lgkmcnt(0)" ::: "memory")

// ------- transpose+split: x (B,C,N) f32 -> xs_h/xs_l (B,N,C) bf16 ------------
__global__ void k_xs(const float* __restrict__ x, u16* __restrict__ xh,
                     u16* __restrict__ xl){
    __shared__ float t[32][33];
    int b = blockIdx.z; int c0 = blockIdx.y*32; int n0 = blockIdx.x*32;
    int tx = threadIdx.x, ty = threadIdx.y;            // (32,8)
    for(int i=ty;i<32;i+=8)
        t[i][tx] = x[((size_t)(b*256 + c0+i))*4096 + n0 + tx];
    __syncthreads();
    for(int i=ty;i<32;i+=8){
        float v = t[tx][i];
        u16 h = f2bf(v);
        size_t o = ((size_t)(b*4096 + n0+i))*256 + c0 + tx;
        xh[o] = h;
        xl[o] = f2bf(v - bf2f(h));
    }
}

// -------- weight transpose+cast: W (K,N) f32 -> WT (N,K) bf16 [perm opt] -----
// perm: dest k index = ((k&15)<<8)|(k>>4)  (unfold reorder)
__global__ void k_wt(const float* __restrict__ W, u16* __restrict__ WT,
                     int K, int N, int perm){
    __shared__ float t[32][33];
    int k0 = blockIdx.x*32, n0 = blockIdx.y*32;
    int tx = threadIdx.x, ty = threadIdx.y;
    for(int i=ty;i<32;i+=8)
        if(k0+i<K && n0+tx<N) t[i][tx] = W[(size_t)(k0+i)*N + n0+tx];
    __syncthreads();
    for(int i=ty;i<32;i+=8)
        if(n0+i<N && k0+tx<K){
            int k = k0+tx;
            int kd = perm ? (((k&15)<<8)|(k>>4)) : k;
            WT[(size_t)(n0+i)*K + kd] = f2bf(t[tx][i]);
        }
}

// -------- split weight transpose: W (K,N) f32 -> (N,K) bf16 hi+lo [perm opt] -
__global__ void k_wt2(const float* __restrict__ W, u16* __restrict__ Hi,
                      u16* __restrict__ Lo, int K, int N, int perm){
    __shared__ float t[32][33];
    int k0 = blockIdx.x*32, n0 = blockIdx.y*32;
    int tx = threadIdx.x, ty = threadIdx.y;
    for(int i=ty;i<32;i+=8)
        if(k0+i<K && n0+tx<N) t[i][tx] = W[(size_t)(k0+i)*N + n0+tx];
    __syncthreads();
    for(int i=ty;i<32;i+=8)
        if(n0+i<N && k0+tx<K){
            int k = k0+tx;
            int kd = perm ? (((k&15)<<8)|(k>>4)) : k;
            float v = t[tx][i];
            u16 h = f2bf(v);
            Hi[(size_t)(n0+i)*K + kd] = h;
            Lo[(size_t)(n0+i)*K + kd] = f2bf(v - bf2f(h));
        }
}

// -------- channel split: qkv f32 -> K field bf16 pair + V field bf16 ---------
__global__ void k_splitkv(const float* __restrict__ qkv, u16* __restrict__ kh,
                          u16* __restrict__ kl, u16* __restrict__ vf){
    int n = blockIdx.x, b = blockIdx.y, c = threadIdx.x;
    size_t src = ((size_t)(b*4096) + n)*768 + c;
    size_t dst = ((size_t)(b*4096) + n)*256 + c;
    float kv = qkv[src + 256];
    u16 h = f2bf(kv);
    kh[dst] = h;
    kl[dst] = f2bf(kv - bf2f(h));
    vf[dst] = f2bf(qkv[src + 512]);
}

// -------- bias' = b1 + pos @ W1 (f32 exact) ----------------------------------
__global__ void k_posw1(const float* __restrict__ pos, const float* __restrict__ W1,
                        const float* __restrict__ b1, float* __restrict__ out){
    __shared__ float part[4][64];
    int tn = threadIdx.x & 63, r = threadIdx.x >> 6;
    int n = blockIdx.x*64 + tn;
    float s = 0.f;
    for(int j=r; j<4096; j+=4)
        s += pos[j] * W1[(size_t)j*512 + n];
    part[r][tn] = s;
    __syncthreads();
    if(threadIdx.x < 64)
        out[n] = b1[n] + (((part[0][tn]+part[1][tn])+part[2][tn])+part[3][tn]);
}

// -------- V transpose: vc rows (b*NK+k)*256+c -> bf16 vt[(b*256+c)*ldk+k] ----
__global__ void k_vt(const float* __restrict__ vc, u16* __restrict__ vt,
                     int NK, int ldk){
    __shared__ float t[32][33];
    int b = blockIdx.z; int k0 = blockIdx.x*32; int c0 = blockIdx.y*32;
    int tx = threadIdx.x, ty = threadIdx.y;
    for(int i=ty;i<32;i+=8){
        int k = k0+i;
        t[i][tx] = (k < NK) ? vc[((size_t)(b*NK + k))*256 + c0 + tx] : 0.f;
    }
    __syncthreads();
    for(int i=ty;i<32;i+=8){
        int k = k0+tx;
        if(k < ldk)
            vt[((size_t)(b*256 + c0+i))*ldk + k] = f2bf(t[tx][i]);
    }
}

// ---------------- f32 GEMM (gate tail only) ----------------------------------
__global__ __launch_bounds__(256) void k_gemm(
        const float* __restrict__ A, const float* __restrict__ W,
        const float* __restrict__ bias, float* __restrict__ C,
        int M, int K, int Nn, int act)
{
    __shared__ float As[16][68];
    __shared__ float Bs[16][64];
    const int m0 = blockIdx.y*64, n0 = blockIdx.x*64;
    const int t = threadIdx.x, tx = t&15, ty = t>>4;
    float acc[4][4] = {};
    const int am = t>>2;
    const int ak = (t&3)*4;
    const bool arow_ok = (m0+am) < M;

    for(int k0=0;k0<K;k0+=16){
        float4 av = make_float4(0.f,0.f,0.f,0.f);
        if(arow_ok) av = *reinterpret_cast<const float4*>(&A[(size_t)(m0+am)*K + k0 + ak]);
        As[ak+0][am]=av.x; As[ak+1][am]=av.y; As[ak+2][am]=av.z; As[ak+3][am]=av.w;
        {
            int n = t&63, kb = t>>6;
            #pragma unroll
            for(int r=0;r<4;r++){
                int kk = r*4 + kb; float v = 0.f;
                if(n0+n < Nn) v = W[(size_t)(k0+kk)*Nn + n0+n];
                Bs[kk][n] = v;
            }
        }
        __syncthreads();
        #pragma unroll
        for(int kk=0;kk<16;kk++){
            float a0=As[kk][ty*4+0], a1=As[kk][ty*4+1], a2=As[kk][ty*4+2], a3=As[kk][ty*4+3];
            float b0=Bs[kk][tx*4+0], b1=Bs[kk][tx*4+1], b2=Bs[kk][tx*4+2], b3=Bs[kk][tx*4+3];
            acc[0][0]=fmaf(a0,b0,acc[0][0]); acc[0][1]=fmaf(a0,b1,acc[0][1]);
            acc[0][2]=fmaf(a0,b2,acc[0][2]); acc[0][3]=fmaf(a0,b3,acc[0][3]);
            acc[1][0]=fmaf(a1,b0,acc[1][0]); acc[1][1]=fmaf(a1,b1,acc[1][1]);
            acc[1][2]=fmaf(a1,b2,acc[1][2]); acc[1][3]=fmaf(a1,b3,acc[1][3]);
            acc[2][0]=fmaf(a2,b0,acc[2][0]); acc[2][1]=fmaf(a2,b1,acc[2][1]);
            acc[2][2]=fmaf(a2,b2,acc[2][2]); acc[2][3]=fmaf(a2,b3,acc[2][3]);
            acc[3][0]=fmaf(a3,b0,acc[3][0]); acc[3][1]=fmaf(a3,b1,acc[3][1]);
            acc[3][2]=fmaf(a3,b2,acc[3][2]); acc[3][3]=fmaf(a3,b3,acc[3][3]);
        }
        __syncthreads();
    }
    #pragma unroll
    for(int i=0;i<4;i++){
        int m = m0 + ty*4 + i;
        if(m >= M) continue;
        #pragma unroll
        for(int j=0;j<4;j++){
            int n = n0 + tx*4 + j;
            if(n >= Nn) continue;
            float v = acc[i][j] + (bias ? bias[n] : 0.f);
            if(act==1)      v = 0.5f*v*(1.0f + erff(v*0.70710678118654752f));
            else if(act==2) v = 1.0f/(1.0f + expf(-v));
            C[(size_t)m*Nn + n] = v;
        }
    }
}

// ===== unified MFMA GEMM: C = scale*(A @ B^T) [+bias][act] ===================
// OBF: 0 = f32 C, 1 = bf16 Cb, 2 = bf16 pair (Cb hi, Cb2 lo).
template<int WM, int WN, int AM, int BMD, int NSPLIT, int OBF>
__global__ __launch_bounds__(256) void k_mgs(
        const float* __restrict__ Af, const u16* __restrict__ Ah,
        const u16* __restrict__ Al,
        const float* __restrict__ Bf, const u16* __restrict__ Bh,
        const u16* __restrict__ Bl,
        const float* __restrict__ bias, float* __restrict__ C,
        u16* __restrict__ Cb, u16* __restrict__ Cb2,
        int M, int N, int K, int lda, int ldb, int ldc, int act, float scale,
        long zsA, long zsB, long zsC)
{
    constexpr int BM = 32*WM, BN = 32*WN;
    constexpr bool SP = (NSPLIT == 3);
    const long zo = (long)blockIdx.z;
    if(AM==0){ Af += zo*zsA; } else { Ah += zo*zsA; if(AM==2) Al += zo*zsA; }
    if(BMD==0){ Bf += zo*zsB; } else { Bh += zo*zsB; if(BMD==2) Bl += zo*zsB; }
    if(OBF) Cb += zo*zsC; else C += zo*zsC;

    __shared__ u16 Ahi[BM*64];
    __shared__ u16 Alo[SP ? BM*64 : 8];
    __shared__ u16 Bhi[BN*64];
    __shared__ u16 Blo[SP ? BN*64 : 8];

    const int m0 = blockIdx.y*BM, n0 = blockIdx.x*BN;
    const int tid = threadIdx.x, lane = tid&63, wv = tid>>6;
    const int wm = (wv>>1)*(16*WM), wn = (wv&1)*(16*WN);
    f32x4 acc[WM][WN] = {};

    constexpr int TPR_A = 256/BM;
    constexpr int CH_A  = 8/TPR_A;
    const int arow = tid / TPR_A;
    const int acol0 = (tid % TPR_A)*(128/TPR_A);
    constexpr int TPR_B = 256/BN;
    constexpr int CH_B  = 8/TPR_B;
    const int brow = tid / TPR_B;
    const int bcol0 = (tid % TPR_B)*(128/TPR_B);

    for(int kt=0; kt<K; kt+=64){
        {
            const bool ok = (m0+arow) < M;
            #pragma unroll
            for(int c=0;c<CH_A;c++){
                int colbyte = acol0 + c*16;
                int e = colbyte>>1;
                const bool lok = ok && (kt + e + 8 <= K);
                short8 h = {}, l = {};
                if(AM==0){
                    float4 v0 = make_float4(0,0,0,0), v1 = v0;
                    if(lok){
                        const float* src = &Af[(size_t)(m0+arow)*lda + kt + e];
                        v0 = *reinterpret_cast<const float4*>(src);
                        v1 = *reinterpret_cast<const float4*>(src+4);
                    }
                    float vv[8] = {v0.x,v0.y,v0.z,v0.w,v1.x,v1.y,v1.z,v1.w};
                    #pragma unroll
                    for(int j=0;j<8;j++){
                        u16 hb = f2bf(vv[j]);
                        h[j] = (short)hb;
                        if(SP) l[j] = (short)f2bf(vv[j] - bf2f(hb));
                    }
                } else {
                    if(lok){
                        h = *reinterpret_cast<const short8*>(Ah + (size_t)(m0+arow)*lda + kt + e);
                        if(SP && AM==2)
                            l = *reinterpret_cast<const short8*>(Al + (size_t)(m0+arow)*lda + kt + e);
                    }
                }
                int byteoff = arow*128 + (colbyte ^ ((arow&7)<<4));
                *reinterpret_cast<short8*>(reinterpret_cast<char*>(Ahi)+byteoff) = h;
                if(SP)
                    *reinterpret_cast<short8*>(reinterpret_cast<char*>(Alo)+byteoff) = l;
            }
        }
        {
            const bool ok = (n0+brow) < N;
            #pragma unroll
            for(int c=0;c<CH_B;c++){
                int colbyte = bcol0 + c*16;
                int e = colbyte>>1;
                const bool lok = ok && (kt + e + 8 <= K);
                short8 h = {}, l = {};
                if(BMD==0){
                    float4 v0 = make_float4(0,0,0,0), v1 = v0;
                    if(lok){
                        const float* src = &Bf[(size_t)(n0+brow)*ldb + kt + e];
                        v0 = *reinterpret_cast<const float4*>(src);
                        v1 = *reinterpret_cast<const float4*>(src+4);
                    }
                    float vv[8] = {v0.x,v0.y,v0.z,v0.w,v1.x,v1.y,v1.z,v1.w};
                    #pragma unroll
                    for(int j=0;j<8;j++){
                        u16 hb = f2bf(vv[j]);
                        h[j] = (short)hb;
                        if(SP) l[j] = (short)f2bf(vv[j] - bf2f(hb));
                    }
                } else {
                    if(lok){
                        h = *reinterpret_cast<const short8*>(Bh + (size_t)(n0+brow)*ldb + kt + e);
                        if(SP && BMD==2)
                            l = *reinterpret_cast<const short8*>(Bl + (size_t)(n0+brow)*ldb + kt + e);
                    }
                }
                int byteoff = brow*128 + (colbyte ^ ((brow&7)<<4));
                *reinterpret_cast<short8*>(reinterpret_cast<char*>(Bhi)+byteoff) = h;
                if(SP)
                    *reinterpret_cast<short8*>(reinterpret_cast<char*>(Blo)+byteoff) = l;
            }
        }
        __syncthreads();
        __builtin_amdgcn_s_setprio(1);
        #pragma unroll
        for(int kb=0;kb<2;kb++){
            short8 ah[WM], al[WM], bh[WN], bl[WN];
            #pragma unroll
            for(int i=0;i<WM;i++){
                int ar = wm + i*16 + (lane&15);
                int ab = ar*128 + (((kb*64) + ((lane>>4)*16)) ^ ((ar&7)<<4));
                ah[i] = *reinterpret_cast<const short8*>(reinterpret_cast<const char*>(Ahi)+ab);
                if(SP)
                    al[i] = *reinterpret_cast<const short8*>(reinterpret_cast<const char*>(Alo)+ab);
            }
            #pragma unroll
            for(int i=0;i<WN;i++){
                int br = wn + i*16 + (lane&15);
                int bb = br*128 + (((kb*64) + ((lane>>4)*16)) ^ ((br&7)<<4));
                bh[i] = *reinterpret_cast<const short8*>(reinterpret_cast<const char*>(Bhi)+bb);
                if(SP)
                    bl[i] = *reinterpret_cast<const short8*>(reinterpret_cast<const char*>(Blo)+bb);
            }
            #pragma unroll
            for(int mi=0;mi<WM;mi++)
                #pragma unroll
                for(int ni=0;ni<WN;ni++){
                    if(SP){
                        acc[mi][ni] = __builtin_amdgcn_mfma_f32_16x16x32_bf16(
                                          al[mi], bh[ni], acc[mi][ni], 0, 0, 0);
                        acc[mi][ni] = __builtin_amdgcn_mfma_f32_16x16x32_bf16(
                                          ah[mi], bl[ni], acc[mi][ni], 0, 0, 0);
                    }
                    acc[mi][ni] = __builtin_amdgcn_mfma_f32_16x16x32_bf16(
                                      ah[mi], bh[ni], acc[mi][ni], 0, 0, 0);
                }
        }
        __builtin_amdgcn_s_setprio(0);
        __syncthreads();
    }
    #pragma unroll
    for(int mi=0;mi<WM;mi++){
        #pragma unroll
        for(int ni=0;ni<WN;ni++){
            int col = n0 + wn + ni*16 + (lane&15);
            if(col >= N) continue;
            int rowb = m0 + wm + mi*16 + ((lane>>4)*4);
            float bv = bias ? bias[col] : 0.f;
            #pragma unroll
            for(int r=0;r<4;r++){
                int m = rowb + r;
                if(m >= M) continue;
                float v = acc[mi][ni][r]*scale + bv;
                if(act==1)      v = 0.5f*v*(1.0f + erff(v*0.70710678118654752f));
                else if(act==2) v = 1.0f/(1.0f + expf(-v));
                if(OBF==2){
                    u16 hb = f2bf(v);
                    Cb [(size_t)m*ldc + col] = hb;
                    Cb2[(size_t)m*ldc + col] = f2bf(v - bf2f(hb));
                } else if(OBF==1){
                    Cb[(size_t)m*ldc + col] = f2bf(v);
                } else {
                    C [(size_t)m*ldc + col] = v;
                }
            }
        }
    }
}

// ===== implicit-unfold MFMA GEMM (compressed K/V first MLP layer) ============
// C(3844,512) = act1( A_unf @ W^T + bias ), A_unf[m][j'] gathered from the
// (b,4096,256) channel field; j' = (kh*4+kw)*256 + ch (weights pre-permuted).
template<int SPLIT>
__global__ __launch_bounds__(256) void k_mgs_unf(
        const u16* __restrict__ Fh, const u16* __restrict__ Fl,
        const u16* __restrict__ Bh, const u16* __restrict__ Bl,
        const float* __restrict__ bias, float* __restrict__ C)
{
    constexpr int M = 3844, N = 512, K = 4096;
    __shared__ u16 Ahi[64*64];
    __shared__ u16 Alo[SPLIT ? 64*64 : 8];
    __shared__ u16 Bhi[64*64];
    __shared__ u16 Blo[SPLIT ? 64*64 : 8];

    const int m0 = blockIdx.y*64, n0 = blockIdx.x*64;
    const int tid = threadIdx.x, lane = tid&63, wv = tid>>6;
    const int wm = (wv>>1)*32, wn = (wv&1)*32;
    f32x4 acc[2][2] = {};

    const int arow = tid >> 2;            // 0..63
    const int acol0 = (tid & 3) * 32;     // byte base
    // per-thread source row decomposition (fixed across K loop)
    const int m = m0 + arow;
    const bool ok = m < M;
    const int mm = ok ? m : 0;
    const int b  = mm / 961;
    const int blk = mm % 961;
    const int bi = blk / 31, bj = blk % 31;
    const u16* fbase_h = Fh + (size_t)b*4096*256;
    const u16* fbase_l = SPLIT ? (Fl + (size_t)b*4096*256) : nullptr;

    for(int kt=0; kt<K; kt+=64){
        {   // stage A via implicit gather
            int sub = kt >> 8;            // kh*4+kw
            int kh = sub >> 2, kw = sub & 3;
            int n = (bi*2 + kh)*64 + (bj*2 + kw);
            size_t srcoff = (size_t)n*256 + (kt & 255);
            #pragma unroll
            for(int c=0;c<2;c++){
                int colbyte = acol0 + c*16;
                int e = colbyte >> 1;
                short8 h = {}, l = {};
                if(ok){
                    h = *reinterpret_cast<const short8*>(fbase_h + srcoff + e);
                    if(SPLIT)
                        l = *reinterpret_cast<const short8*>(fbase_l + srcoff + e);
                }
                int byteoff = arow*128 + (colbyte ^ ((arow&7)<<4));
                *reinterpret_cast<short8*>(reinterpret_cast<char*>(Ahi)+byteoff) = h;
                if(SPLIT)
                    *reinterpret_cast<short8*>(reinterpret_cast<char*>(Alo)+byteoff) = l;
            }
        }
        {   // stage B (permuted weights, contiguous)
            int brow = tid >> 2;
            int bcol0 = (tid & 3) * 32;
            #pragma unroll
            for(int c=0;c<2;c++){
                int colbyte = bcol0 + c*16;
                int e = colbyte >> 1;
                short8 h = *reinterpret_cast<const short8*>(Bh + (size_t)(n0+brow)*K + kt + e);
                short8 l = {};
                if(SPLIT)
                    l = *reinterpret_cast<const short8*>(Bl + (size_t)(n0+brow)*K + kt + e);
                int byteoff = brow*128 + (colbyte ^ ((brow&7)<<4));
                *reinterpret_cast<short8*>(reinterpret_cast<char*>(Bhi)+byteoff) = h;
                if(SPLIT)
                    *reinterpret_cast<short8*>(reinterpret_cast<char*>(Blo)+byteoff) = l;
            }
        }
        __syncthreads();
        __builtin_amdgcn_s_setprio(1);
        #pragma unroll
        for(int kb=0;kb<2;kb++){
            short8 ah[2], al[2], bh[2], bl[2];
            #pragma unroll
            for(int i=0;i<2;i++){
                int ar = wm + i*16 + (lane&15);
                int ab = ar*128 + (((kb*64) + ((lane>>4)*16)) ^ ((ar&7)<<4));
                ah[i] = *reinterpret_cast<const short8*>(reinterpret_cast<const char*>(Ahi)+ab);
                if(SPLIT)
                    al[i] = *reinterpret_cast<const short8*>(reinterpret_cast<const char*>(Alo)+ab);
            }
            #pragma unroll
            for(int i=0;i<2;i++){
                int br = wn + i*16 + (lane&15);
                int bb = br*128 + (((kb*64) + ((lane>>4)*16)) ^ ((br&7)<<4));
                bh[i] = *reinterpret_cast<const short8*>(reinterpret_cast<const char*>(Bhi)+bb);
                if(SPLIT)
                    bl[i] = *reinterpret_cast<const short8*>(reinterpret_cast<const char*>(Blo)+bb);
            }
            #pragma unroll
            for(int mi=0;mi<2;mi++)
                #pragma unroll
                for(int ni=0;ni<2;ni++){
                    if(SPLIT){
                        acc[mi][ni] = __builtin_amdgcn_mfma_f32_16x16x32_bf16(
                                          al[mi], bh[ni], acc[mi][ni], 0, 0, 0);
                        acc[mi][ni] = __builtin_amdgcn_mfma_f32_16x16x32_bf16(
                                          ah[mi], bl[ni], acc[mi][ni], 0, 0, 0);
                    }
                    acc[mi][ni] = __builtin_amdgcn_mfma_f32_16x16x32_bf16(
                                      ah[mi], bh[ni], acc[mi][ni], 0, 0, 0);
                }
        }
        __builtin_amdgcn_s_setprio(0);
        __syncthreads();
    }
    #pragma unroll
    for(int mi=0;mi<2;mi++){
        #pragma unroll
        for(int ni=0;ni<2;ni++){
            int col = n0 + wn + ni*16 + (lane&15);
            int rowb = m0 + wm + mi*16 + ((lane>>4)*4);
            float bv = bias[col];
            #pragma unroll
            for(int r=0;r<4;r++){
                int mr = rowb + r;
                if(mr >= M) continue;
                float v = acc[mi][ni][r] + bv;
                v = 0.5f*v*(1.0f + erff(v*0.70710678118654752f));  // GELU
                C[(size_t)mr*512 + col] = v;
            }
        }
    }
}

// ====== fused flash attention, no-max softmax, T14 staging, bf16 O ===========
template<int SPLIT, int IMP, int ONEPASS, int NKR, int NT, int LDV>
__global__ __launch_bounds__(256) void k_fattn(
    const float* __restrict__ Qg, const u16* __restrict__ Khg,
    const u16* __restrict__ Klg, const u16* __restrict__ VTg,
    u16* __restrict__ Og, float* __restrict__ impp)
{
    const int qb = blockIdx.x, h = blockIdx.y, b = blockIdx.z;
    const int tid = threadIdx.x, lane = tid&63, wv = tid>>6;
    const int wm = wv*16;
    const int rgrp = lane>>4;      // 0..3
    const int cidx = lane&15;

    __shared__ u16 Qh[64*64];
    __shared__ u16 Ql[SPLIT?64*64:8];
    __shared__ u16 Kh[64*64];
    __shared__ u16 Kl[SPLIT?64*64:8];
    __shared__ u16 Pl[64*64];
    __shared__ u16 Vl[64*64];
    __shared__ float part[4][64];
    __shared__ float colacc[IMP? NT*64 : 8];

    const int srow = tid>>2;
    const int scol0 = (tid&3)*32;

    short8 kh_r[2], kl_r[2], v_r[2];

    auto LK = [&](int t){
        const bool ok = (t*64 + srow) < NKR;
        const u16* srch = &Khg[((size_t)b*NKR + t*64 + srow)*256 + h*64];
        const u16* srcl = SPLIT ? &Klg[((size_t)b*NKR + t*64 + srow)*256 + h*64] : nullptr;
        #pragma unroll
        for(int c=0;c<2;c++){
            int e = (scol0 + c*16)>>1;
            short8 hh = {}, ll = {};
            if(ok){
                hh = *reinterpret_cast<const short8*>(srch+e);
                if(SPLIT) ll = *reinterpret_cast<const short8*>(srcl+e);
            }
            kh_r[c] = hh;
            if(SPLIT) kl_r[c] = ll;
        }
    };
    auto WK = [&](){
        #pragma unroll
        for(int c=0;c<2;c++){
            int colbyte = scol0 + c*16;
            int byteoff = srow*128 + (colbyte ^ ((srow&7)<<4));
            *reinterpret_cast<short8*>(reinterpret_cast<char*>(Kh)+byteoff) = kh_r[c];
            if(SPLIT)
                *reinterpret_cast<short8*>(reinterpret_cast<char*>(Kl)+byteoff) = kl_r[c];
        }
    };
    auto LV = [&](int t){
        const u16* src = &VTg[((size_t)b*256 + h*64 + srow)*LDV + t*64];
        #pragma unroll
        for(int c=0;c<2;c++){
            int e = (scol0 + c*16)>>1;
            short8 hh = {};
            if(t*64 + e + 8 <= LDV)
                hh = *reinterpret_cast<const short8*>(src + e);
            v_r[c] = hh;
        }
    };
    auto WV = [&](){
        #pragma unroll
        for(int c=0;c<2;c++){
            int colbyte = scol0 + c*16;
            int byteoff = srow*128 + (colbyte ^ ((srow&7)<<4));
            *reinterpret_cast<short8*>(reinterpret_cast<char*>(Vl)+byteoff) = v_r[c];
        }
    };

    {
        const float* src = &Qg[((size_t)b*4096 + qb*64 + srow)*768 + h*64];
        #pragma unroll
        for(int c=0;c<2;c++){
            int colbyte = scol0 + c*16;
            int e = colbyte>>1;
            float4 v0 = *reinterpret_cast<const float4*>(src+e);
            float4 v1 = *reinterpret_cast<const float4*>(src+e+4);
            float vv[8]={v0.x,v0.y,v0.z,v0.w,v1.x,v1.y,v1.z,v1.w};
            short8 hh, ll;
            #pragma unroll
            for(int j=0;j<8;j++){
                u16 hb=f2bf(vv[j]); hh[j]=(short)hb;
                if(SPLIT) ll[j]=(short)f2bf(vv[j]-bf2f(hb));
            }
            int byteoff = srow*128 + (colbyte ^ ((srow&7)<<4));
            *reinterpret_cast<short8*>(reinterpret_cast<char*>(Qh)+byteoff)=hh;
            if(SPLIT)
                *reinterpret_cast<short8*>(reinterpret_cast<char*>(Ql)+byteoff)=ll;
        }
        if(IMP) for(int k=tid;k<NT*64;k+=256) colacc[k]=0.f;
    }

    float lsum[4] = {0.f,0.f,0.f,0.f};
    float inv[4];
    f32x4 acc_o[4] = {};

    if(!ONEPASS){
        LK(0);
        for(int t=0;t<NT;t++){
            const int kt = t*64;
            LGKM0();
            __builtin_amdgcn_s_barrier();
            WK();
            if(t+1<NT) LK(t+1);
            LGKM0();
            __builtin_amdgcn_s_barrier();
            f32x4 acc[4] = {};
            __builtin_amdgcn_s_setprio(1);
            #pragma unroll
            for(int kb=0;kb<2;kb++){
                int koff = kb*64 + rgrp*16;
                int ar = wm + cidx;
                int ab = ar*128 + (koff ^ ((ar&7)<<4));
                short8 ah = *reinterpret_cast<const short8*>(reinterpret_cast<const char*>(Qh)+ab);
                short8 al;
                if(SPLIT) al = *reinterpret_cast<const short8*>(reinterpret_cast<const char*>(Ql)+ab);
                #pragma unroll
                for(int ni=0;ni<4;ni++){
                    int br = ni*16 + cidx;
                    int bb = br*128 + (koff ^ ((br&7)<<4));
                    short8 bh = *reinterpret_cast<const short8*>(reinterpret_cast<const char*>(Kh)+bb);
                    if(SPLIT){
                        short8 bl = *reinterpret_cast<const short8*>(reinterpret_cast<const char*>(Kl)+bb);
                        acc[ni] = __builtin_amdgcn_mfma_f32_16x16x32_bf16(al, bh, acc[ni], 0,0,0);
                        acc[ni] = __builtin_amdgcn_mfma_f32_16x16x32_bf16(ah, bl, acc[ni], 0,0,0);
                    }
                    acc[ni] = __builtin_amdgcn_mfma_f32_16x16x32_bf16(ah, bh, acc[ni], 0,0,0);
                }
            }
            __builtin_amdgcn_s_setprio(0);
            #pragma unroll
            for(int ni=0;ni<4;ni++){
                int col = kt + ni*16 + cidx;
                if(col < NKR){
                    #pragma unroll
                    for(int r=0;r<4;r++)
                        lsum[r] += __expf(acc[ni][r]*0.125f);
                }
            }
        }
        #pragma unroll
        for(int r=0;r<4;r++){
            float l = lsum[r];
            l += __shfl_xor(l,1); l += __shfl_xor(l,2);
            l += __shfl_xor(l,4); l += __shfl_xor(l,8);
            inv[r] = 1.f/l;
        }
    }

    LK(0); LV(0);
    for(int t=0;t<NT;t++){
        const int kt = t*64;
        LGKM0();
        __builtin_amdgcn_s_barrier();
        WK(); WV();
        if(t+1<NT){ LK(t+1); LV(t+1); }
        LGKM0();
        __builtin_amdgcn_s_barrier();
        f32x4 acc[4] = {};
        __builtin_amdgcn_s_setprio(1);
        #pragma unroll
        for(int kb=0;kb<2;kb++){
            int koff = kb*64 + rgrp*16;
            int ar = wm + cidx;
            int ab = ar*128 + (koff ^ ((ar&7)<<4));
            short8 ah = *reinterpret_cast<const short8*>(reinterpret_cast<const char*>(Qh)+ab);
            short8 al;
            if(SPLIT) al = *reinterpret_cast<const short8*>(reinterpret_cast<const char*>(Ql)+ab);
            #pragma unroll
            for(int ni=0;ni<4;ni++){
                int br = ni*16 + cidx;
                int bb = br*128 + (koff ^ ((br&7)<<4));
                short8 bh = *reinterpret_cast<const short8*>(reinterpret_cast<const char*>(Kh)+bb);
                if(SPLIT){
                    short8 bl = *reinterpret_cast<const short8*>(reinterpret_cast<const char*>(Kl)+bb);
                    acc[ni] = __builtin_amdgcn_mfma_f32_16x16x32_bf16(al, bh, acc[ni], 0,0,0);
                    acc[ni] = __builtin_amdgcn_mfma_f32_16x16x32_bf16(ah, bl, acc[ni], 0,0,0);
                }
                acc[ni] = __builtin_amdgcn_mfma_f32_16x16x32_bf16(ah, bh, acc[ni], 0,0,0);
            }
        }
        __builtin_amdgcn_s_setprio(0);
        float cs[4] = {0.f,0.f,0.f,0.f};
        #pragma unroll
        for(int ni=0;ni<4;ni++){
            #pragma unroll
            for(int r=0;r<4;r++){
                int col = kt + ni*16 + cidx;
                float p = 0.f;
                if(col < NKR){
                    p = __expf(acc[ni][r]*0.125f);
                    if(!ONEPASS) p *= inv[r];
                    else lsum[r] += p;
                }
                int prow = wm + rgrp*4 + r;
                int pcol = ni*16 + cidx;
                int byteoff = prow*128 + ((pcol*2) ^ ((prow&7)<<4));
                *reinterpret_cast<u16*>(reinterpret_cast<char*>(Pl)+byteoff) = f2bf(p);
                if(IMP) cs[ni] += p;
            }
        }
        if(IMP){
            #pragma unroll
            for(int ni=0;ni<4;ni++){
                cs[ni] += __shfl_xor(cs[ni],16);
                cs[ni] += __shfl_xor(cs[ni],32);
            }
            if(rgrp==0){
                #pragma unroll
                for(int ni=0;ni<4;ni++)
                    part[wv][ni*16+cidx] = cs[ni];
            }
        }
        LGKM0();
        __builtin_amdgcn_s_barrier();
        if(IMP && tid < 64)
            colacc[kt+tid] += ((part[0][tid]+part[1][tid])+part[2][tid])+part[3][tid];
        __builtin_amdgcn_s_setprio(1);
        #pragma unroll
        for(int kb=0;kb<2;kb++){
            int koff = kb*64 + rgrp*16;
            int ar = wm + cidx;
            int ab = ar*128 + (koff ^ ((ar&7)<<4));
            short8 pa = *reinterpret_cast<const short8*>(reinterpret_cast<const char*>(Pl)+ab);
            #pragma unroll
            for(int ni=0;ni<4;ni++){
                int br = ni*16 + cidx;
                int bb = br*128 + (koff ^ ((br&7)<<4));
                short8 vb = *reinterpret_cast<const short8*>(reinterpret_cast<const char*>(Vl)+bb);
                acc_o[ni] = __builtin_amdgcn_mfma_f32_16x16x32_bf16(pa, vb, acc_o[ni], 0,0,0);
            }
        }
        __builtin_amdgcn_s_setprio(0);
    }
    if(ONEPASS){
        #pragma unroll
        for(int r=0;r<4;r++){
            float l = lsum[r];
            l += __shfl_xor(l,1); l += __shfl_xor(l,2);
            l += __shfl_xor(l,4); l += __shfl_xor(l,8);
            inv[r] = 1.f/l;
        }
    }
    __syncthreads();
    #pragma unroll
    for(int ni=0;ni<4;ni++){
        #pragma unroll
        for(int r=0;r<4;r++){
            int q = qb*64 + wm + rgrp*4 + r;
            int d = ni*16 + cidx;
            float o = acc_o[ni][r];
            if(ONEPASS) o *= inv[r];
            Og[((size_t)b*4096 + q)*256 + h*64 + d] = f2bf(o);
        }
    }
    if(IMP){
        size_t base = ((size_t)((b*4+h)*64) + qb)*976;
        for(int k=tid; k<NT*64 && k<976; k+=256)
            impp[base+k] = colacc[k];
    }
}

// ------------- deterministic importance reduce (256 rows/b) ------------------
__global__ void k_imp_reduce(const float* __restrict__ impp, float* __restrict__ imp){
    __shared__ float part[4][64];
    int b = blockIdx.y;
    int k = blockIdx.x*64 + (threadIdx.x & 63);
    int rr = threadIdx.x >> 6;
    float s = 0.f;
    if(k < 976){
        for(int r=rr; r<256; r+=4)
            s += impp[((size_t)(b*256) + r)*976 + k];
    }
    part[rr][threadIdx.x & 63] = s;
    __syncthreads();
    if(threadIdx.x < 64 && k < 961){
        float t = ((part[0][threadIdx.x] + part[1][threadIdx.x])
                 + part[2][threadIdx.x]) + part[3][threadIdx.x];
        imp[b*961 + k] = t;
    }
}

// ------------- top-16, parallel argmax, lowest-index tie-break ---------------
__global__ __launch_bounds__(256) void k_topk(const float* __restrict__ imp,
                                              int* __restrict__ idx){
    int b = blockIdx.x;
    __shared__ float v[961];
    __shared__ float wvv[4];
    __shared__ int   wvi[4];
    int t = threadIdx.x;
    int lane = t & 63, wid = t >> 6;
    for(int i=t;i<961;i+=256) v[i] = imp[b*961+i];
    __syncthreads();
    for(int it=0; it<16; it++){
        float bv = -1e30f; int bi = 1<<30;
        for(int i=t;i<961;i+=256){
            float val = v[i];
            if(val > bv){ bv=val; bi=i; }
        }
        #pragma unroll
        for(int off=32; off>0; off>>=1){
            float ov = __shfl_xor(bv, off);
            int   oi = __shfl_xor(bi, off);
            if(ov > bv || (ov == bv && oi < bi)){ bv = ov; bi = oi; }
        }
        if(lane==0){ wvv[wid]=bv; wvi[wid]=bi; }
        __syncthreads();
        if(t==0){
            float gb=wvv[0]; int gi=wvi[0];
            #pragma unroll
            for(int w=1;w<4;w++){
                if(wvv[w]>gb || (wvv[w]==gb && wvi[w]<gi)){ gb=wvv[w]; gi=wvi[w]; }
            }
            idx[b*16+it] = gi;
            v[gi] = -1e30f;
        }
        __syncthreads();
    }
}

// ------------- gather selected K/V (quirk layout, clip to 255) ----------------
__global__ void k_gather_sel(const float* __restrict__ qkv2, const int* __restrict__ idx,
                             u16* __restrict__ Ks, float* __restrict__ Vs){
    int row = blockIdx.x;            // b*256 + t ; t = sel*16 + p
    int b = row >> 8, tt = row & 255;
    int sel = tt >> 4, p = tt & 15;
    int blk = idx[b*16+sel]; if(blk > 255) blk = 255;
    int bi = blk >> 4, bj = blk & 15;
    int cc = threadIdx.x;
    int y = bi*4 + ((cc>>2)&3), xx = bj*4 + (cc&3);
    int ch = p*16 + (cc>>4);
    size_t src = ((size_t)(b*4096) + y*64 + xx)*768;
    Ks[(size_t)row*256 + cc] = f2bf(qkv2[src + 256 + ch]);
    Vs[(size_t)row*256 + cc] = qkv2[src + 512 + ch];
}

// ------------- build padded window tokens xw (bf16) --------------------------
__global__ void k_xw(const u16* __restrict__ xh, u16* __restrict__ xw){
    int row = blockIdx.x;             // wb*49 + t
    int wb = row / 49, t = row % 49;
    int b = wb / 100, wrem = wb % 100;
    int wy = wrem / 10, wx = wrem % 10;
    int ty = t / 7, tx = t % 7;
    int y = wy*7 + ty, xx = wx*7 + tx;
    int c = threadIdx.x;
    u16 v = 0;
    if(y < 64 && xx < 64) v = xh[((size_t)(b*4096) + y*64 + xx)*256 + c];
    xw[(size_t)row*256 + c] = v;
}

// ------------- window attention: 49 tokens, rel-pos bias; bf16 in/out --------
__global__ __launch_bounds__(64) void k_attn_win(
    const u16* __restrict__ qkvw, const float* __restrict__ btab,
    u16* __restrict__ outp)
{
    const int wb = blockIdx.x, h = blockIdx.y;
    const int lane = threadIdx.x;
    __shared__ float lk[49][64];
    __shared__ float lv[49][64];
    __shared__ float ls[49][51];
    __shared__ float lbias[169];
    for(int i=lane;i<169;i+=64) lbias[i] = btab[i*4 + h];
    for(int r=0;r<49;r++){
        lk[r][lane] = bf2f(qkvw[((size_t)(wb*49 + r))*768 + 256 + h*64 + lane]);
        lv[r][lane] = bf2f(qkvw[((size_t)(wb*49 + r))*768 + 512 + h*64 + lane]);
    }
    __syncthreads();
    if(lane < 49){
        const u16* qptr = &qkvw[((size_t)(wb*49 + lane))*768 + h*64];
        float qreg[64];
        #pragma unroll
        for(int d=0;d<64;++d) qreg[d] = bf2f(qptr[d]);
        int ih = lane/7, iw = lane%7;
        float m = -1e30f;
        for(int j=0;j<49;j++){
            float s0=0,s1=0,s2=0,s3=0;
            #pragma unroll
            for(int d=0; d<64; d+=4){
                s0 = fmaf(qreg[d+0], lk[j][d+0], s0);
                s1 = fmaf(qreg[d+1], lk[j][d+1], s1);
                s2 = fmaf(qreg[d+2], lk[j][d+2], s2);
                s3 = fmaf(qreg[d+3], lk[j][d+3], s3);
            }
            int jh=j/7, jw=j%7;
            float s = ((s0+s1)+(s2+s3))*0.125f + lbias[(ih-jh+6)*13 + (iw-jw+6)];
            ls[lane][j] = s;
            m = fmaxf(m, s);
        }
        float l = 0.f;
        for(int j=0;j<49;j++){ float p = __expf(ls[lane][j] - m); ls[lane][j] = p; l += p; }
        float inv = 1.f/l;
        u16* op = &outp[((size_t)(wb*49 + lane))*256 + h*64];
        for(int d=0;d<64;d++){
            float a0=0,a1=0;
            for(int j=0;j<48;j+=2){
                a0 = fmaf(ls[lane][j],   lv[j][d],   a0);
                a1 = fmaf(ls[lane][j+1], lv[j+1][d], a1);
            }
            a0 = fmaf(ls[lane][48], lv[48][d], a0);
            op[d] = f2bf((a0+a1)*inv);
        }
    }
}

// ------------- final gated combine + transpose to (B,C,H,W) f32 -------------
__global__ void k_combine(const float* __restrict__ ocp, const float* __restrict__ osp,
                          const float* __restrict__ owp, const float* __restrict__ g,
                          float* __restrict__ out){
    __shared__ float tile[32][33];
    int b = blockIdx.z; int c0 = blockIdx.y*32, n0 = blockIdx.x*32;
    int tx = threadIdx.x, ty = threadIdx.y;    // (32,8)
    for(int i=ty;i<32;i+=8){
        int n = n0 + i;
        float g0 = g[(size_t)(b*4096+n)*3 + 0];
        float g1 = g[(size_t)(b*4096+n)*3 + 1];
        float g2 = g[(size_t)(b*4096+n)*3 + 2];
        int y = n >> 6, xx = n & 63;
        int wy = y/7, ty2 = y%7, wx = xx/7, tx2 = xx%7;
        size_t wrow = (size_t)(b*100 + wy*10 + wx)*49 + ty2*7 + tx2;
        size_t base = ((size_t)(b*4096) + n)*256 + c0;
        float vc = ocp[base + tx];
        float vs = osp[base + tx];
        float vw = owp[wrow*256 + c0 + tx];
        tile[i][tx] = g0*vc + g1*vs + g2*vw;
    }
    __syncthreads();
    for(int i=ty;i<32;i+=8)
        out[((size_t)(b*256 + c0+i))*4096 + n0 + tx] = tile[tx][i];
}

// =============================== host side ===================================
extern "C" void kernel_launch(void* const* d_in, const int* in_sizes, int n_in,
                              void* d_out, int out_size, void* d_ws, size_t ws_size,
                              hipStream_t stream)
{
    typedef const float* fp;
    fp x          = (fp)d_in[0];
    fp qkv_cmp_w  = (fp)d_in[1];  fp qkv_cmp_b = (fp)d_in[2];
    fp qkv_slc_w  = (fp)d_in[3];  fp qkv_slc_b = (fp)d_in[4];
    fp cmpk_w1    = (fp)d_in[5];  fp cmpk_b1   = (fp)d_in[6];
    fp cmpk_w2    = (fp)d_in[7];  fp cmpk_b2   = (fp)d_in[8];
    fp cmpv_w1    = (fp)d_in[9];  fp cmpv_b1   = (fp)d_in[10];
    fp cmpv_w2    = (fp)d_in[11]; fp cmpv_b2   = (fp)d_in[12];
    fp pos_embed  = (fp)d_in[13];
    fp win_qkv_w  = (fp)d_in[14]; fp win_qkv_b = (fp)d_in[15];
    fp win_proj_w = (fp)d_in[16]; fp win_proj_b= (fp)d_in[17];
    fp win_btab   = (fp)d_in[18];
    fp proj_cmp_w = (fp)d_in[19]; fp proj_cmp_b= (fp)d_in[20];
    fp proj_slc_w = (fp)d_in[21]; fp proj_slc_b= (fp)d_in[22];
    fp gate_w1    = (fp)d_in[23]; fp gate_b1   = (fp)d_in[24];
    fp gate_w2    = (fp)d_in[25]; fp gate_b2   = (fp)d_in[26];
    (void)in_sizes; (void)n_in; (void)out_size;

    char* ws = (char*)d_ws;
    size_t off = 0;
    auto alloc = [&](size_t bytes)->size_t{
        size_t r = off; off += (bytes + 255) & ~(size_t)255; return r;
    };
    const size_t XSH  = alloc((size_t)16384*256*2);
    const size_t XSL  = alloc((size_t)16384*256*2);
    const size_t QKV  = alloc((size_t)16384*768*4);
    const size_t BIGA = alloc((size_t)4*4096*976*4);   // qkvw / out_win / out_slc
    const size_t HID  = alloc((size_t)3844*512*4);
    const size_t KCH  = alloc((size_t)3844*256*2);
    const size_t KCL  = alloc((size_t)3844*256*2);
    const size_t VC   = alloc((size_t)3844*256*4);
    const size_t S_IMPP = (size_t)4096*976*4;
    const size_t S_OC   = (size_t)16384*256*4;
    const size_t S_PB   = (size_t)4*4096*976*2;
    const size_t POOL = alloc(S_IMPP + S_OC + S_OC + S_PB);
    const size_t IMP  = alloc((size_t)4*961*4);
    const size_t IDX  = alloc((size_t)4*16*4);
    const size_t KS   = alloc((size_t)4*256*256*2);
    const size_t VS   = alloc((size_t)4*256*256*4);
    const size_t G2   = alloc((size_t)16384*3*4);
    const size_t VTC  = alloc((size_t)4*256*976*2);
    const size_t VTS  = alloc((size_t)4*256*256*2);
    const size_t POSB = alloc((size_t)512*4);
    const size_t TQS  = alloc((size_t)768*256*2);
    const size_t TWQ  = alloc((size_t)768*256*2);
    const size_t TV1  = alloc((size_t)512*4096*2);
    const size_t TV2  = alloc((size_t)256*512*2);
    const size_t TPC  = alloc((size_t)256*256*2);
    const size_t TPS  = alloc((size_t)256*256*2);
    const size_t TWP  = alloc((size_t)256*256*2);
    const size_t TG1  = alloc((size_t)64*256*2);
    const size_t TQCH = alloc((size_t)768*256*2);
    const size_t TQCL = alloc((size_t)768*256*2);
    const size_t TK1H = alloc((size_t)512*4096*2);
    const size_t TK1L = alloc((size_t)512*4096*2);
    const size_t TK2H = alloc((size_t)256*512*2);
    const size_t TK2L = alloc((size_t)256*512*2);
    if(off > ws_size) return;   // ~247 MB (budget proven)

    u16*   p_xsh = (u16*)(ws + XSH);
    u16*   p_xsl = (u16*)(ws + XSL);
    float* p_qkv = (float*)(ws + QKV);
    u16*   p_bigb= (u16*)  (ws + BIGA);
    float* p_oslc= (float*)(ws + BIGA);
    float* p_owp = (float*)(ws + BIGA + 20971520);
    float* p_hid = (float*)(ws + HID);
    u16*   p_kch = (u16*)(ws + KCH);
    u16*   p_kcl = (u16*)(ws + KCL);
    float* p_vc  = (float*)(ws + VC);
    float* p_impp= (float*)(ws + POOL);
    u16*   p_oc16= (u16*)  (ws + POOL + S_IMPP);
    float* p_ocp = (float*)(ws + POOL + S_IMPP + S_OC);
    // K/V channel fields alias POOL (dead before impp/oc16 writes at step 9)
    u16*   p_kfh = (u16*)  (ws + POOL);
    u16*   p_kfl = p_kfh + (size_t)4*4096*256;
    u16*   p_vf  = p_kfl + (size_t)4*4096*256;
    u16*   p_xwb = (u16*)  (ws + POOL);
    u16*   p_owin= (u16*)  (ws + POOL + S_IMPP);
    float* p_imp = (float*)(ws + IMP);
    int*   p_idx = (int*)  (ws + IDX);
    u16*   p_ks  = (u16*)(ws + KS);
    float* p_vs  = (float*)(ws + VS);
    float* p_g   = (float*)(ws + G2);
    u16*   p_vtc = (u16*)(ws + VTC);
    u16*   p_vts = (u16*)(ws + VTS);
    float* p_posb= (float*)(ws + POSB);
    u16* t_qs = (u16*)(ws + TQS);
    u16* t_wq = (u16*)(ws + TWQ);
    u16* t_v1 = (u16*)(ws + TV1);
    u16* t_v2 = (u16*)(ws + TV2);
    u16* t_pc = (u16*)(ws + TPC);
    u16* t_ps = (u16*)(ws + TPS);
    u16* t_wp = (u16*)(ws + TWP);
    u16* t_g1 = (u16*)(ws + TG1);
    u16* t_qch= (u16*)(ws + TQCH);
    u16* t_qcl= (u16*)(ws + TQCL);
    u16* t_k1h= (u16*)(ws + TK1H);
    u16* t_k1l= (u16*)(ws + TK1L);
    u16* t_k2h= (u16*)(ws + TK2H);
    u16* t_k2l= (u16*)(ws + TK2L);

    auto wt = [&](fp W, u16* WT, int K, int Nn, int perm){
        k_wt<<<dim3((K+31)/32, (Nn+31)/32), dim3(32,8), 0, stream>>>(W, WT, K, Nn, perm);
    };
    auto wt2 = [&](fp W, u16* H, u16* L, int K, int Nn, int perm){
        k_wt2<<<dim3((K+31)/32, (Nn+31)/32), dim3(32,8), 0, stream>>>(W, H, L, K, Nn, perm);
    };

    // 0. weight preprocessing (w1 matrices K-permuted for implicit unfold)
    wt(qkv_slc_w, t_qs, 256, 768, 0);
    wt(win_qkv_w, t_wq, 256, 768, 0);
    wt(cmpv_w1,   t_v1, 4096, 512, 1);
    wt(cmpv_w2,   t_v2, 512, 256, 0);
    wt(proj_cmp_w,t_pc, 256, 256, 0);
    wt(proj_slc_w,t_ps, 256, 256, 0);
    wt(win_proj_w,t_wp, 256, 256, 0);
    wt(gate_w1,   t_g1, 256, 64, 0);
    wt2(qkv_cmp_w, t_qch, t_qcl, 256, 768, 0);
    wt2(cmpk_w1,   t_k1h, t_k1l, 4096, 512, 1);
    wt2(cmpk_w2,   t_k2h, t_k2l, 512, 256, 0);
    k_posw1<<<8, 256, 0, stream>>>(pos_embed, cmpk_w1, cmpk_b1, p_posb);

    // 1. xs (bf16 hi/lo)
    k_xs<<<dim3(128,8,4), dim3(32,8), 0, stream>>>(x, p_xsh, p_xsl);
    // 2. qkv_cmp (split, A pair, B pair)
    k_mgs<4,4,2,2,3,0><<<dim3(6,128), 256, 0, stream>>>(
        nullptr, p_xsh, p_xsl, nullptr, t_qch, t_qcl, qkv_cmp_b, p_qkv, nullptr, nullptr,
        16384, 768, 256, 256, 256, 768, 0, 1.0f, 0, 0, 0);
    // 3. channel split: K field pair + V field (POOL alias)
    k_splitkv<<<dim3(4096,4), 256, 0, stream>>>(p_qkv, p_kfh, p_kfl, p_vf);
    // 4-5. compressed K path (implicit-unfold split GEMM; pos folded in bias)
    k_mgs_unf<1><<<dim3(8,61), 256, 0, stream>>>(
        p_kfh, p_kfl, t_k1h, t_k1l, p_posb, p_hid);
    k_mgs<2,2,0,2,3,2><<<dim3(4,61), 256, 0, stream>>>(
        p_hid, nullptr, nullptr, nullptr, t_k2h, t_k2l, cmpk_b2, nullptr, p_kch, p_kcl,
        3844, 256, 512, 512, 512, 256, 0, 1.0f, 0, 0, 0);
    // 6-7. compressed V path (implicit-unfold single GEMM)
    k_mgs_unf<0><<<dim3(8,61), 256, 0, stream>>>(
        p_vf, nullptr, t_v1, nullptr, cmpv_b1, p_hid);
    k_mgs<2,2,0,1,1,0><<<dim3(4,61), 256, 0, stream>>>(
        p_hid, nullptr, nullptr, nullptr, t_v2, nullptr, cmpv_b2, p_vc, nullptr, nullptr,
        3844, 256, 512, 512, 512, 256, 0, 1.0f, 0, 0, 0);
    // V^T bf16 (zero-padded to 976)
    k_vt<<<dim3(31,8,4), dim3(32,8), 0, stream>>>(p_vc, p_vtc, 961, 976);
    // 9. compressed attention — fused flash (2-pass, importance), bf16 O
    k_fattn<1,1,0,961,16,976><<<dim3(64,4,4), 256, 0, stream>>>(
        p_qkv, p_kch, p_kcl, p_vtc, p_oc16, p_impp);
    k_imp_reduce<<<dim3(16,4), 256, 0, stream>>>(p_impp, p_imp);
    k_topk<<<4, 256, 0, stream>>>(p_imp, p_idx);
    // 10. out_cmp projection (bf16 A)
    k_mgs<4,4,1,1,1,0><<<dim3(2,128), 256, 0, stream>>>(
        nullptr, p_oc16, nullptr, nullptr, t_pc, nullptr, proj_cmp_b, p_ocp, nullptr, nullptr,
        16384, 256, 256, 256, 256, 256, 0, 1.0f, 0, 0, 0);
    // 11. qkv_slc (A = xs hi bf16)
    k_mgs<4,4,1,1,1,0><<<dim3(6,128), 256, 0, stream>>>(
        nullptr, p_xsh, nullptr, nullptr, t_qs, nullptr, qkv_slc_b, p_qkv, nullptr, nullptr,
        16384, 768, 256, 256, 256, 768, 0, 1.0f, 0, 0, 0);
    // 12-14. window branch
    k_xw<<<19600, 256, 0, stream>>>(p_xsh, p_xwb);
    k_mgs<4,4,1,1,1,1><<<dim3(6,154), 256, 0, stream>>>(
        nullptr, p_xwb, nullptr, nullptr, t_wq, nullptr, win_qkv_b, nullptr, p_bigb, nullptr,
        19600, 768, 256, 256, 256, 768, 0, 1.0f, 0, 0, 0);
    k_attn_win<<<dim3(400,4), 64, 0, stream>>>(p_bigb, win_btab, p_owin);
    k_mgs<4,4,1,1,1,0><<<dim3(2,154), 256, 0, stream>>>(
        nullptr, p_owin, nullptr, nullptr, t_wp, nullptr, win_proj_b, p_owp, nullptr, nullptr,
        19600, 256, 256, 256, 256, 256, 0, 1.0f, 0, 0, 0);
    // 15-16. selected branch — single-pass fused flash, bf16 O
    k_gather_sel<<<1024, 256, 0, stream>>>(p_qkv, p_idx, p_ks, p_vs);
    k_vt<<<dim3(8,8,4), dim3(32,8), 0, stream>>>(p_vs, p_vts, 256, 256);
    k_fattn<0,0,1,256,4,256><<<dim3(64,4,4), 256, 0, stream>>>(
        p_qkv, p_ks, nullptr, p_vts, p_oc16, nullptr);
    // 17. out_slc projection (bf16 A)
    k_mgs<4,4,1,1,1,0><<<dim3(2,128), 256, 0, stream>>>(
        nullptr, p_oc16, nullptr, nullptr, t_ps, nullptr, proj_slc_b, p_oslc, nullptr, nullptr,
        16384, 256, 256, 256, 256, 256, 0, 1.0f, 0, 0, 0);
    // 18-19. gate
    k_mgs<2,2,1,1,1,0><<<dim3(1,256), 256, 0, stream>>>(
        nullptr, p_xsh, nullptr, nullptr, t_g1, nullptr, gate_b1, p_hid, nullptr, nullptr,
        16384, 64, 256, 256, 256, 64, 1, 1.0f, 0, 0, 0);
    k_gemm<<<dim3(1,256), 256, 0, stream>>>(p_hid, gate_w2, gate_b2, p_g,
                                            16384, 64, 3, 2);
    // 20. combine
    k_combine<<<dim3(128,8,4), dim3(32,8), 0, stream>>>(p_ocp, p_oslc, p_owp, p_g,
                                                        (float*)d_out);
}

// Round 20
// 753.161 us; speedup vs baseline: 1.3177x; 1.3177x over previous
//
#include <hip/hip_runtime.h>
#include <stdint.h>
#include <stddef.h>

// SpatialNSA on MI355X — round 20: fix round-19's grid-starved k_posw1
// (8 blocks, 255us, 0.36% occupancy) -> two-stage 512-block reduction (~8us).
// Everything else identical to round 19.

#define DEV __device__ __forceinline__

typedef __attribute__((ext_vector_type(8))) short short8;
typedef __attribute__((ext_vector_type(4))) float f32x4;
typedef unsigned short u16;

DEV u16 f2bf(float f){
    unsigned u = __float_as_uint(f);
    u += 0x7FFFu + ((u>>16)&1u);   // RNE
    return (u16)(u>>16);
}
DEV float bf2f(u16 u){ return __uint_as_float(((unsigned)u)<<16); }

#define LGKM0() asm volatile("s_waitcnt lgkmcnt(0)" ::: "memory")

// ------- transpose+split: x (B,C,N) f32 -> xs_h/xs_l (B,N,C) bf16 ------------
__global__ void k_xs(const float* __restrict__ x, u16* __restrict__ xh,
                     u16* __restrict__ xl){
    __shared__ float t[32][33];
    int b = blockIdx.z; int c0 = blockIdx.y*32; int n0 = blockIdx.x*32;
    int tx = threadIdx.x, ty = threadIdx.y;            // (32,8)
    for(int i=ty;i<32;i+=8)
        t[i][tx] = x[((size_t)(b*256 + c0+i))*4096 + n0 + tx];
    __syncthreads();
    for(int i=ty;i<32;i+=8){
        float v = t[tx][i];
        u16 h = f2bf(v);
        size_t o = ((size_t)(b*4096 + n0+i))*256 + c0 + tx;
        xh[o] = h;
        xl[o] = f2bf(v - bf2f(h));
    }
}

// -------- weight transpose+cast: W (K,N) f32 -> WT (N,K) bf16 [perm opt] -----
__global__ void k_wt(const float* __restrict__ W, u16* __restrict__ WT,
                     int K, int N, int perm){
    __shared__ float t[32][33];
    int k0 = blockIdx.x*32, n0 = blockIdx.y*32;
    int tx = threadIdx.x, ty = threadIdx.y;
    for(int i=ty;i<32;i+=8)
        if(k0+i<K && n0+tx<N) t[i][tx] = W[(size_t)(k0+i)*N + n0+tx];
    __syncthreads();
    for(int i=ty;i<32;i+=8)
        if(n0+i<N && k0+tx<K){
            int k = k0+tx;
            int kd = perm ? (((k&15)<<8)|(k>>4)) : k;
            WT[(size_t)(n0+i)*K + kd] = f2bf(t[tx][i]);
        }
}

// -------- split weight transpose: W (K,N) f32 -> (N,K) bf16 hi+lo [perm opt] -
__global__ void k_wt2(const float* __restrict__ W, u16* __restrict__ Hi,
                      u16* __restrict__ Lo, int K, int N, int perm){
    __shared__ float t[32][33];
    int k0 = blockIdx.x*32, n0 = blockIdx.y*32;
    int tx = threadIdx.x, ty = threadIdx.y;
    for(int i=ty;i<32;i+=8)
        if(k0+i<K && n0+tx<N) t[i][tx] = W[(size_t)(k0+i)*N + n0+tx];
    __syncthreads();
    for(int i=ty;i<32;i+=8)
        if(n0+i<N && k0+tx<K){
            int k = k0+tx;
            int kd = perm ? (((k&15)<<8)|(k>>4)) : k;
            float v = t[tx][i];
            u16 h = f2bf(v);
            Hi[(size_t)(n0+i)*K + kd] = h;
            Lo[(size_t)(n0+i)*K + kd] = f2bf(v - bf2f(h));
        }
}

// -------- channel split: qkv f32 -> K field bf16 pair + V field bf16 ---------
__global__ void k_splitkv(const float* __restrict__ qkv, u16* __restrict__ kh,
                          u16* __restrict__ kl, u16* __restrict__ vf){
    int n = blockIdx.x, b = blockIdx.y, c = threadIdx.x;
    size_t src = ((size_t)(b*4096) + n)*768 + c;
    size_t dst = ((size_t)(b*4096) + n)*256 + c;
    float kv = qkv[src + 256];
    u16 h = f2bf(kv);
    kh[dst] = h;
    kl[dst] = f2bf(kv - bf2f(h));
    vf[dst] = f2bf(qkv[src + 512]);
}

// -------- pos @ W1 stage 1: 512-block partial sums ---------------------------
// grid (8, 64): block covers n in [bx*64,..), j in [by*64,..). Block 256 thr
// = 64 n-cols x 4 j-groups. out pp[by*512 + n].
__global__ void k_posw1a(const float* __restrict__ pos, const float* __restrict__ W1,
                         float* __restrict__ pp){
    __shared__ float part[4][64];
    int tn = threadIdx.x & 63, r = threadIdx.x >> 6;
    int n = blockIdx.x*64 + tn;
    int j0 = blockIdx.y*64;
    float s = 0.f;
    for(int jj=r; jj<64; jj+=4)
        s += pos[j0+jj] * W1[(size_t)(j0+jj)*512 + n];
    part[r][tn] = s;
    __syncthreads();
    if(threadIdx.x < 64)
        pp[(size_t)blockIdx.y*512 + n] =
            ((part[0][tn]+part[1][tn])+part[2][tn])+part[3][tn];
}

// -------- pos @ W1 stage 2: reduce 64 partials + b1 --------------------------
__global__ void k_posw1b(const float* __restrict__ pp, const float* __restrict__ b1,
                         float* __restrict__ out){
    int n = blockIdx.x*256 + threadIdx.x;
    float s = 0.f;
    for(int r=0;r<64;r++) s += pp[(size_t)r*512 + n];
    out[n] = b1[n] + s;
}

// -------- V transpose: vc rows (b*NK+k)*256+c -> bf16 vt[(b*256+c)*ldk+k] ----
__global__ void k_vt(const float* __restrict__ vc, u16* __restrict__ vt,
                     int NK, int ldk){
    __shared__ float t[32][33];
    int b = blockIdx.z; int k0 = blockIdx.x*32; int c0 = blockIdx.y*32;
    int tx = threadIdx.x, ty = threadIdx.y;
    for(int i=ty;i<32;i+=8){
        int k = k0+i;
        t[i][tx] = (k < NK) ? vc[((size_t)(b*NK + k))*256 + c0 + tx] : 0.f;
    }
    __syncthreads();
    for(int i=ty;i<32;i+=8){
        int k = k0+tx;
        if(k < ldk)
            vt[((size_t)(b*256 + c0+i))*ldk + k] = f2bf(t[tx][i]);
    }
}

// ---------------- f32 GEMM (gate tail only) ----------------------------------
__global__ __launch_bounds__(256) void k_gemm(
        const float* __restrict__ A, const float* __restrict__ W,
        const float* __restrict__ bias, float* __restrict__ C,
        int M, int K, int Nn, int act)
{
    __shared__ float As[16][68];
    __shared__ float Bs[16][64];
    const int m0 = blockIdx.y*64, n0 = blockIdx.x*64;
    const int t = threadIdx.x, tx = t&15, ty = t>>4;
    float acc[4][4] = {};
    const int am = t>>2;
    const int ak = (t&3)*4;
    const bool arow_ok = (m0+am) < M;

    for(int k0=0;k0<K;k0+=16){
        float4 av = make_float4(0.f,0.f,0.f,0.f);
        if(arow_ok) av = *reinterpret_cast<const float4*>(&A[(size_t)(m0+am)*K + k0 + ak]);
        As[ak+0][am]=av.x; As[ak+1][am]=av.y; As[ak+2][am]=av.z; As[ak+3][am]=av.w;
        {
            int n = t&63, kb = t>>6;
            #pragma unroll
            for(int r=0;r<4;r++){
                int kk = r*4 + kb; float v = 0.f;
                if(n0+n < Nn) v = W[(size_t)(k0+kk)*Nn + n0+n];
                Bs[kk][n] = v;
            }
        }
        __syncthreads();
        #pragma unroll
        for(int kk=0;kk<16;kk++){
            float a0=As[kk][ty*4+0], a1=As[kk][ty*4+1], a2=As[kk][ty*4+2], a3=As[kk][ty*4+3];
            float b0=Bs[kk][tx*4+0], b1=Bs[kk][tx*4+1], b2=Bs[kk][tx*4+2], b3=Bs[kk][tx*4+3];
            acc[0][0]=fmaf(a0,b0,acc[0][0]); acc[0][1]=fmaf(a0,b1,acc[0][1]);
            acc[0][2]=fmaf(a0,b2,acc[0][2]); acc[0][3]=fmaf(a0,b3,acc[0][3]);
            acc[1][0]=fmaf(a1,b0,acc[1][0]); acc[1][1]=fmaf(a1,b1,acc[1][1]);
            acc[1][2]=fmaf(a1,b2,acc[1][2]); acc[1][3]=fmaf(a1,b3,acc[1][3]);
            acc[2][0]=fmaf(a2,b0,acc[2][0]); acc[2][1]=fmaf(a2,b1,acc[2][1]);
            acc[2][2]=fmaf(a2,b2,acc[2][2]); acc[2][3]=fmaf(a2,b3,acc[2][3]);
            acc[3][0]=fmaf(a3,b0,acc[3][0]); acc[3][1]=fmaf(a3,b1,acc[3][1]);
            acc[3][2]=fmaf(a3,b2,acc[3][2]); acc[3][3]=fmaf(a3,b3,acc[3][3]);
        }
        __syncthreads();
    }
    #pragma unroll
    for(int i=0;i<4;i++){
        int m = m0 + ty*4 + i;
        if(m >= M) continue;
        #pragma unroll
        for(int j=0;j<4;j++){
            int n = n0 + tx*4 + j;
            if(n >= Nn) continue;
            float v = acc[i][j] + (bias ? bias[n] : 0.f);
            if(act==1)      v = 0.5f*v*(1.0f + erff(v*0.70710678118654752f));
            else if(act==2) v = 1.0f/(1.0f + expf(-v));
            C[(size_t)m*Nn + n] = v;
        }
    }
}

// ===== unified MFMA GEMM: C = scale*(A @ B^T) [+bias][act] ===================
template<int WM, int WN, int AM, int BMD, int NSPLIT, int OBF>
__global__ __launch_bounds__(256) void k_mgs(
        const float* __restrict__ Af, const u16* __restrict__ Ah,
        const u16* __restrict__ Al,
        const float* __restrict__ Bf, const u16* __restrict__ Bh,
        const u16* __restrict__ Bl,
        const float* __restrict__ bias, float* __restrict__ C,
        u16* __restrict__ Cb, u16* __restrict__ Cb2,
        int M, int N, int K, int lda, int ldb, int ldc, int act, float scale,
        long zsA, long zsB, long zsC)
{
    constexpr int BM = 32*WM, BN = 32*WN;
    constexpr bool SP = (NSPLIT == 3);
    const long zo = (long)blockIdx.z;
    if(AM==0){ Af += zo*zsA; } else { Ah += zo*zsA; if(AM==2) Al += zo*zsA; }
    if(BMD==0){ Bf += zo*zsB; } else { Bh += zo*zsB; if(BMD==2) Bl += zo*zsB; }
    if(OBF) Cb += zo*zsC; else C += zo*zsC;

    __shared__ u16 Ahi[BM*64];
    __shared__ u16 Alo[SP ? BM*64 : 8];
    __shared__ u16 Bhi[BN*64];
    __shared__ u16 Blo[SP ? BN*64 : 8];

    const int m0 = blockIdx.y*BM, n0 = blockIdx.x*BN;
    const int tid = threadIdx.x, lane = tid&63, wv = tid>>6;
    const int wm = (wv>>1)*(16*WM), wn = (wv&1)*(16*WN);
    f32x4 acc[WM][WN] = {};

    constexpr int TPR_A = 256/BM;
    constexpr int CH_A  = 8/TPR_A;
    const int arow = tid / TPR_A;
    const int acol0 = (tid % TPR_A)*(128/TPR_A);
    constexpr int TPR_B = 256/BN;
    constexpr int CH_B  = 8/TPR_B;
    const int brow = tid / TPR_B;
    const int bcol0 = (tid % TPR_B)*(128/TPR_B);

    for(int kt=0; kt<K; kt+=64){
        {
            const bool ok = (m0+arow) < M;
            #pragma unroll
            for(int c=0;c<CH_A;c++){
                int colbyte = acol0 + c*16;
                int e = colbyte>>1;
                const bool lok = ok && (kt + e + 8 <= K);
                short8 h = {}, l = {};
                if(AM==0){
                    float4 v0 = make_float4(0,0,0,0), v1 = v0;
                    if(lok){
                        const float* src = &Af[(size_t)(m0+arow)*lda + kt + e];
                        v0 = *reinterpret_cast<const float4*>(src);
                        v1 = *reinterpret_cast<const float4*>(src+4);
                    }
                    float vv[8] = {v0.x,v0.y,v0.z,v0.w,v1.x,v1.y,v1.z,v1.w};
                    #pragma unroll
                    for(int j=0;j<8;j++){
                        u16 hb = f2bf(vv[j]);
                        h[j] = (short)hb;
                        if(SP) l[j] = (short)f2bf(vv[j] - bf2f(hb));
                    }
                } else {
                    if(lok){
                        h = *reinterpret_cast<const short8*>(Ah + (size_t)(m0+arow)*lda + kt + e);
                        if(SP && AM==2)
                            l = *reinterpret_cast<const short8*>(Al + (size_t)(m0+arow)*lda + kt + e);
                    }
                }
                int byteoff = arow*128 + (colbyte ^ ((arow&7)<<4));
                *reinterpret_cast<short8*>(reinterpret_cast<char*>(Ahi)+byteoff) = h;
                if(SP)
                    *reinterpret_cast<short8*>(reinterpret_cast<char*>(Alo)+byteoff) = l;
            }
        }
        {
            const bool ok = (n0+brow) < N;
            #pragma unroll
            for(int c=0;c<CH_B;c++){
                int colbyte = bcol0 + c*16;
                int e = colbyte>>1;
                const bool lok = ok && (kt + e + 8 <= K);
                short8 h = {}, l = {};
                if(BMD==0){
                    float4 v0 = make_float4(0,0,0,0), v1 = v0;
                    if(lok){
                        const float* src = &Bf[(size_t)(n0+brow)*ldb + kt + e];
                        v0 = *reinterpret_cast<const float4*>(src);
                        v1 = *reinterpret_cast<const float4*>(src+4);
                    }
                    float vv[8] = {v0.x,v0.y,v0.z,v0.w,v1.x,v1.y,v1.z,v1.w};
                    #pragma unroll
                    for(int j=0;j<8;j++){
                        u16 hb = f2bf(vv[j]);
                        h[j] = (short)hb;
                        if(SP) l[j] = (short)f2bf(vv[j] - bf2f(hb));
                    }
                } else {
                    if(lok){
                        h = *reinterpret_cast<const short8*>(Bh + (size_t)(n0+brow)*ldb + kt + e);
                        if(SP && BMD==2)
                            l = *reinterpret_cast<const short8*>(Bl + (size_t)(n0+brow)*ldb + kt + e);
                    }
                }
                int byteoff = brow*128 + (colbyte ^ ((brow&7)<<4));
                *reinterpret_cast<short8*>(reinterpret_cast<char*>(Bhi)+byteoff) = h;
                if(SP)
                    *reinterpret_cast<short8*>(reinterpret_cast<char*>(Blo)+byteoff) = l;
            }
        }
        __syncthreads();
        __builtin_amdgcn_s_setprio(1);
        #pragma unroll
        for(int kb=0;kb<2;kb++){
            short8 ah[WM], al[WM], bh[WN], bl[WN];
            #pragma unroll
            for(int i=0;i<WM;i++){
                int ar = wm + i*16 + (lane&15);
                int ab = ar*128 + (((kb*64) + ((lane>>4)*16)) ^ ((ar&7)<<4));
                ah[i] = *reinterpret_cast<const short8*>(reinterpret_cast<const char*>(Ahi)+ab);
                if(SP)
                    al[i] = *reinterpret_cast<const short8*>(reinterpret_cast<const char*>(Alo)+ab);
            }
            #pragma unroll
            for(int i=0;i<WN;i++){
                int br = wn + i*16 + (lane&15);
                int bb = br*128 + (((kb*64) + ((lane>>4)*16)) ^ ((br&7)<<4));
                bh[i] = *reinterpret_cast<const short8*>(reinterpret_cast<const char*>(Bhi)+bb);
                if(SP)
                    bl[i] = *reinterpret_cast<const short8*>(reinterpret_cast<const char*>(Blo)+bb);
            }
            #pragma unroll
            for(int mi=0;mi<WM;mi++)
                #pragma unroll
                for(int ni=0;ni<WN;ni++){
                    if(SP){
                        acc[mi][ni] = __builtin_amdgcn_mfma_f32_16x16x32_bf16(
                                          al[mi], bh[ni], acc[mi][ni], 0, 0, 0);
                        acc[mi][ni] = __builtin_amdgcn_mfma_f32_16x16x32_bf16(
                                          ah[mi], bl[ni], acc[mi][ni], 0, 0, 0);
                    }
                    acc[mi][ni] = __builtin_amdgcn_mfma_f32_16x16x32_bf16(
                                      ah[mi], bh[ni], acc[mi][ni], 0, 0, 0);
                }
        }
        __builtin_amdgcn_s_setprio(0);
        __syncthreads();
    }
    #pragma unroll
    for(int mi=0;mi<WM;mi++){
        #pragma unroll
        for(int ni=0;ni<WN;ni++){
            int col = n0 + wn + ni*16 + (lane&15);
            if(col >= N) continue;
            int rowb = m0 + wm + mi*16 + ((lane>>4)*4);
            float bv = bias ? bias[col] : 0.f;
            #pragma unroll
            for(int r=0;r<4;r++){
                int m = rowb + r;
                if(m >= M) continue;
                float v = acc[mi][ni][r]*scale + bv;
                if(act==1)      v = 0.5f*v*(1.0f + erff(v*0.70710678118654752f));
                else if(act==2) v = 1.0f/(1.0f + expf(-v));
                if(OBF==2){
                    u16 hb = f2bf(v);
                    Cb [(size_t)m*ldc + col] = hb;
                    Cb2[(size_t)m*ldc + col] = f2bf(v - bf2f(hb));
                } else if(OBF==1){
                    Cb[(size_t)m*ldc + col] = f2bf(v);
                } else {
                    C [(size_t)m*ldc + col] = v;
                }
            }
        }
    }
}

// ===== implicit-unfold MFMA GEMM (compressed K/V first MLP layer) ============
template<int SPLIT>
__global__ __launch_bounds__(256) void k_mgs_unf(
        const u16* __restrict__ Fh, const u16* __restrict__ Fl,
        const u16* __restrict__ Bh, const u16* __restrict__ Bl,
        const float* __restrict__ bias, float* __restrict__ C)
{
    constexpr int M = 3844, N = 512, K = 4096;
    __shared__ u16 Ahi[64*64];
    __shared__ u16 Alo[SPLIT ? 64*64 : 8];
    __shared__ u16 Bhi[64*64];
    __shared__ u16 Blo[SPLIT ? 64*64 : 8];

    const int m0 = blockIdx.y*64, n0 = blockIdx.x*64;
    const int tid = threadIdx.x, lane = tid&63, wv = tid>>6;
    const int wm = (wv>>1)*32, wn = (wv&1)*32;
    f32x4 acc[2][2] = {};

    const int arow = tid >> 2;
    const int acol0 = (tid & 3) * 32;
    const int m = m0 + arow;
    const bool ok = m < M;
    const int mm = ok ? m : 0;
    const int b  = mm / 961;
    const int blk = mm % 961;
    const int bi = blk / 31, bj = blk % 31;
    const u16* fbase_h = Fh + (size_t)b*4096*256;
    const u16* fbase_l = SPLIT ? (Fl + (size_t)b*4096*256) : nullptr;

    for(int kt=0; kt<K; kt+=64){
        {
            int sub = kt >> 8;
            int kh = sub >> 2, kw = sub & 3;
            int n = (bi*2 + kh)*64 + (bj*2 + kw);
            size_t srcoff = (size_t)n*256 + (kt & 255);
            #pragma unroll
            for(int c=0;c<2;c++){
                int colbyte = acol0 + c*16;
                int e = colbyte >> 1;
                short8 h = {}, l = {};
                if(ok){
                    h = *reinterpret_cast<const short8*>(fbase_h + srcoff + e);
                    if(SPLIT)
                        l = *reinterpret_cast<const short8*>(fbase_l + srcoff + e);
                }
                int byteoff = arow*128 + (colbyte ^ ((arow&7)<<4));
                *reinterpret_cast<short8*>(reinterpret_cast<char*>(Ahi)+byteoff) = h;
                if(SPLIT)
                    *reinterpret_cast<short8*>(reinterpret_cast<char*>(Alo)+byteoff) = l;
            }
        }
        {
            int brow = tid >> 2;
            int bcol0 = (tid & 3) * 32;
            #pragma unroll
            for(int c=0;c<2;c++){
                int colbyte = bcol0 + c*16;
                int e = colbyte >> 1;
                short8 h = *reinterpret_cast<const short8*>(Bh + (size_t)(n0+brow)*K + kt + e);
                short8 l = {};
                if(SPLIT)
                    l = *reinterpret_cast<const short8*>(Bl + (size_t)(n0+brow)*K + kt + e);
                int byteoff = brow*128 + (colbyte ^ ((brow&7)<<4));
                *reinterpret_cast<short8*>(reinterpret_cast<char*>(Bhi)+byteoff) = h;
                if(SPLIT)
                    *reinterpret_cast<short8*>(reinterpret_cast<char*>(Blo)+byteoff) = l;
            }
        }
        __syncthreads();
        __builtin_amdgcn_s_setprio(1);
        #pragma unroll
        for(int kb=0;kb<2;kb++){
            short8 ah[2], al[2], bh[2], bl[2];
            #pragma unroll
            for(int i=0;i<2;i++){
                int ar = wm + i*16 + (lane&15);
                int ab = ar*128 + (((kb*64) + ((lane>>4)*16)) ^ ((ar&7)<<4));
                ah[i] = *reinterpret_cast<const short8*>(reinterpret_cast<const char*>(Ahi)+ab);
                if(SPLIT)
                    al[i] = *reinterpret_cast<const short8*>(reinterpret_cast<const char*>(Alo)+ab);
            }
            #pragma unroll
            for(int i=0;i<2;i++){
                int br = wn + i*16 + (lane&15);
                int bb = br*128 + (((kb*64) + ((lane>>4)*16)) ^ ((br&7)<<4));
                bh[i] = *reinterpret_cast<const short8*>(reinterpret_cast<const char*>(Bhi)+bb);
                if(SPLIT)
                    bl[i] = *reinterpret_cast<const short8*>(reinterpret_cast<const char*>(Blo)+bb);
            }
            #pragma unroll
            for(int mi=0;mi<2;mi++)
                #pragma unroll
                for(int ni=0;ni<2;ni++){
                    if(SPLIT){
                        acc[mi][ni] = __builtin_amdgcn_mfma_f32_16x16x32_bf16(
                                          al[mi], bh[ni], acc[mi][ni], 0, 0, 0);
                        acc[mi][ni] = __builtin_amdgcn_mfma_f32_16x16x32_bf16(
                                          ah[mi], bl[ni], acc[mi][ni], 0, 0, 0);
                    }
                    acc[mi][ni] = __builtin_amdgcn_mfma_f32_16x16x32_bf16(
                                      ah[mi], bh[ni], acc[mi][ni], 0, 0, 0);
                }
        }
        __builtin_amdgcn_s_setprio(0);
        __syncthreads();
    }
    #pragma unroll
    for(int mi=0;mi<2;mi++){
        #pragma unroll
        for(int ni=0;ni<2;ni++){
            int col = n0 + wn + ni*16 + (lane&15);
            int rowb = m0 + wm + mi*16 + ((lane>>4)*4);
            float bv = bias[col];
            #pragma unroll
            for(int r=0;r<4;r++){
                int mr = rowb + r;
                if(mr >= M) continue;
                float v = acc[mi][ni][r] + bv;
                v = 0.5f*v*(1.0f + erff(v*0.70710678118654752f));  // GELU
                C[(size_t)mr*512 + col] = v;
            }
        }
    }
}

// ====== fused flash attention, no-max softmax, T14 staging, bf16 O ===========
template<int SPLIT, int IMP, int ONEPASS, int NKR, int NT, int LDV>
__global__ __launch_bounds__(256) void k_fattn(
    const float* __restrict__ Qg, const u16* __restrict__ Khg,
    const u16* __restrict__ Klg, const u16* __restrict__ VTg,
    u16* __restrict__ Og, float* __restrict__ impp)
{
    const int qb = blockIdx.x, h = blockIdx.y, b = blockIdx.z;
    const int tid = threadIdx.x, lane = tid&63, wv = tid>>6;
    const int wm = wv*16;
    const int rgrp = lane>>4;      // 0..3
    const int cidx = lane&15;

    __shared__ u16 Qh[64*64];
    __shared__ u16 Ql[SPLIT?64*64:8];
    __shared__ u16 Kh[64*64];
    __shared__ u16 Kl[SPLIT?64*64:8];
    __shared__ u16 Pl[64*64];
    __shared__ u16 Vl[64*64];
    __shared__ float part[4][64];
    __shared__ float colacc[IMP? NT*64 : 8];

    const int srow = tid>>2;
    const int scol0 = (tid&3)*32;

    short8 kh_r[2], kl_r[2], v_r[2];

    auto LK = [&](int t){
        const bool ok = (t*64 + srow) < NKR;
        const u16* srch = &Khg[((size_t)b*NKR + t*64 + srow)*256 + h*64];
        const u16* srcl = SPLIT ? &Klg[((size_t)b*NKR + t*64 + srow)*256 + h*64] : nullptr;
        #pragma unroll
        for(int c=0;c<2;c++){
            int e = (scol0 + c*16)>>1;
            short8 hh = {}, ll = {};
            if(ok){
                hh = *reinterpret_cast<const short8*>(srch+e);
                if(SPLIT) ll = *reinterpret_cast<const short8*>(srcl+e);
            }
            kh_r[c] = hh;
            if(SPLIT) kl_r[c] = ll;
        }
    };
    auto WK = [&](){
        #pragma unroll
        for(int c=0;c<2;c++){
            int colbyte = scol0 + c*16;
            int byteoff = srow*128 + (colbyte ^ ((srow&7)<<4));
            *reinterpret_cast<short8*>(reinterpret_cast<char*>(Kh)+byteoff) = kh_r[c];
            if(SPLIT)
                *reinterpret_cast<short8*>(reinterpret_cast<char*>(Kl)+byteoff) = kl_r[c];
        }
    };
    auto LV = [&](int t){
        const u16* src = &VTg[((size_t)b*256 + h*64 + srow)*LDV + t*64];
        #pragma unroll
        for(int c=0;c<2;c++){
            int e = (scol0 + c*16)>>1;
            short8 hh = {};
            if(t*64 + e + 8 <= LDV)
                hh = *reinterpret_cast<const short8*>(src + e);
            v_r[c] = hh;
        }
    };
    auto WV = [&](){
        #pragma unroll
        for(int c=0;c<2;c++){
            int colbyte = scol0 + c*16;
            int byteoff = srow*128 + (colbyte ^ ((srow&7)<<4));
            *reinterpret_cast<short8*>(reinterpret_cast<char*>(Vl)+byteoff) = v_r[c];
        }
    };

    {
        const float* src = &Qg[((size_t)b*4096 + qb*64 + srow)*768 + h*64];
        #pragma unroll
        for(int c=0;c<2;c++){
            int colbyte = scol0 + c*16;
            int e = colbyte>>1;
            float4 v0 = *reinterpret_cast<const float4*>(src+e);
            float4 v1 = *reinterpret_cast<const float4*>(src+e+4);
            float vv[8]={v0.x,v0.y,v0.z,v0.w,v1.x,v1.y,v1.z,v1.w};
            short8 hh, ll;
            #pragma unroll
            for(int j=0;j<8;j++){
                u16 hb=f2bf(vv[j]); hh[j]=(short)hb;
                if(SPLIT) ll[j]=(short)f2bf(vv[j]-bf2f(hb));
            }
            int byteoff = srow*128 + (colbyte ^ ((srow&7)<<4));
            *reinterpret_cast<short8*>(reinterpret_cast<char*>(Qh)+byteoff)=hh;
            if(SPLIT)
                *reinterpret_cast<short8*>(reinterpret_cast<char*>(Ql)+byteoff)=ll;
        }
        if(IMP) for(int k=tid;k<NT*64;k+=256) colacc[k]=0.f;
    }

    float lsum[4] = {0.f,0.f,0.f,0.f};
    float inv[4];
    f32x4 acc_o[4] = {};

    if(!ONEPASS){
        LK(0);
        for(int t=0;t<NT;t++){
            const int kt = t*64;
            LGKM0();
            __builtin_amdgcn_s_barrier();
            WK();
            if(t+1<NT) LK(t+1);
            LGKM0();
            __builtin_amdgcn_s_barrier();
            f32x4 acc[4] = {};
            __builtin_amdgcn_s_setprio(1);
            #pragma unroll
            for(int kb=0;kb<2;kb++){
                int koff = kb*64 + rgrp*16;
                int ar = wm + cidx;
                int ab = ar*128 + (koff ^ ((ar&7)<<4));
                short8 ah = *reinterpret_cast<const short8*>(reinterpret_cast<const char*>(Qh)+ab);
                short8 al;
                if(SPLIT) al = *reinterpret_cast<const short8*>(reinterpret_cast<const char*>(Ql)+ab);
                #pragma unroll
                for(int ni=0;ni<4;ni++){
                    int br = ni*16 + cidx;
                    int bb = br*128 + (koff ^ ((br&7)<<4));
                    short8 bh = *reinterpret_cast<const short8*>(reinterpret_cast<const char*>(Kh)+bb);
                    if(SPLIT){
                        short8 bl = *reinterpret_cast<const short8*>(reinterpret_cast<const char*>(Kl)+bb);
                        acc[ni] = __builtin_amdgcn_mfma_f32_16x16x32_bf16(al, bh, acc[ni], 0,0,0);
                        acc[ni] = __builtin_amdgcn_mfma_f32_16x16x32_bf16(ah, bl, acc[ni], 0,0,0);
                    }
                    acc[ni] = __builtin_amdgcn_mfma_f32_16x16x32_bf16(ah, bh, acc[ni], 0,0,0);
                }
            }
            __builtin_amdgcn_s_setprio(0);
            #pragma unroll
            for(int ni=0;ni<4;ni++){
                int col = kt + ni*16 + cidx;
                if(col < NKR){
                    #pragma unroll
                    for(int r=0;r<4;r++)
                        lsum[r] += __expf(acc[ni][r]*0.125f);
                }
            }
        }
        #pragma unroll
        for(int r=0;r<4;r++){
            float l = lsum[r];
            l += __shfl_xor(l,1); l += __shfl_xor(l,2);
            l += __shfl_xor(l,4); l += __shfl_xor(l,8);
            inv[r] = 1.f/l;
        }
    }

    LK(0); LV(0);
    for(int t=0;t<NT;t++){
        const int kt = t*64;
        LGKM0();
        __builtin_amdgcn_s_barrier();
        WK(); WV();
        if(t+1<NT){ LK(t+1); LV(t+1); }
        LGKM0();
        __builtin_amdgcn_s_barrier();
        f32x4 acc[4] = {};
        __builtin_amdgcn_s_setprio(1);
        #pragma unroll
        for(int kb=0;kb<2;kb++){
            int koff = kb*64 + rgrp*16;
            int ar = wm + cidx;
            int ab = ar*128 + (koff ^ ((ar&7)<<4));
            short8 ah = *reinterpret_cast<const short8*>(reinterpret_cast<const char*>(Qh)+ab);
            short8 al;
            if(SPLIT) al = *reinterpret_cast<const short8*>(reinterpret_cast<const char*>(Ql)+ab);
            #pragma unroll
            for(int ni=0;ni<4;ni++){
                int br = ni*16 + cidx;
                int bb = br*128 + (koff ^ ((br&7)<<4));
                short8 bh = *reinterpret_cast<const short8*>(reinterpret_cast<const char*>(Kh)+bb);
                if(SPLIT){
                    short8 bl = *reinterpret_cast<const short8*>(reinterpret_cast<const char*>(Kl)+bb);
                    acc[ni] = __builtin_amdgcn_mfma_f32_16x16x32_bf16(al, bh, acc[ni], 0,0,0);
                    acc[ni] = __builtin_amdgcn_mfma_f32_16x16x32_bf16(ah, bl, acc[ni], 0,0,0);
                }
                acc[ni] = __builtin_amdgcn_mfma_f32_16x16x32_bf16(ah, bh, acc[ni], 0,0,0);
            }
        }
        __builtin_amdgcn_s_setprio(0);
        float cs[4] = {0.f,0.f,0.f,0.f};
        #pragma unroll
        for(int ni=0;ni<4;ni++){
            #pragma unroll
            for(int r=0;r<4;r++){
                int col = kt + ni*16 + cidx;
                float p = 0.f;
                if(col < NKR){
                    p = __expf(acc[ni][r]*0.125f);
                    if(!ONEPASS) p *= inv[r];
                    else lsum[r] += p;
                }
                int prow = wm + rgrp*4 + r;
                int pcol = ni*16 + cidx;
                int byteoff = prow*128 + ((pcol*2) ^ ((prow&7)<<4));
                *reinterpret_cast<u16*>(reinterpret_cast<char*>(Pl)+byteoff) = f2bf(p);
                if(IMP) cs[ni] += p;
            }
        }
        if(IMP){
            #pragma unroll
            for(int ni=0;ni<4;ni++){
                cs[ni] += __shfl_xor(cs[ni],16);
                cs[ni] += __shfl_xor(cs[ni],32);
            }
            if(rgrp==0){
                #pragma unroll
                for(int ni=0;ni<4;ni++)
                    part[wv][ni*16+cidx] = cs[ni];
            }
        }
        LGKM0();
        __builtin_amdgcn_s_barrier();
        if(IMP && tid < 64)
            colacc[kt+tid] += ((part[0][tid]+part[1][tid])+part[2][tid])+part[3][tid];
        __builtin_amdgcn_s_setprio(1);
        #pragma unroll
        for(int kb=0;kb<2;kb++){
            int koff = kb*64 + rgrp*16;
            int ar = wm + cidx;
            int ab = ar*128 + (koff ^ ((ar&7)<<4));
            short8 pa = *reinterpret_cast<const short8*>(reinterpret_cast<const char*>(Pl)+ab);
            #pragma unroll
            for(int ni=0;ni<4;ni++){
                int br = ni*16 + cidx;
                int bb = br*128 + (koff ^ ((br&7)<<4));
                short8 vb = *reinterpret_cast<const short8*>(reinterpret_cast<const char*>(Vl)+bb);
                acc_o[ni] = __builtin_amdgcn_mfma_f32_16x16x32_bf16(pa, vb, acc_o[ni], 0,0,0);
            }
        }
        __builtin_amdgcn_s_setprio(0);
    }
    if(ONEPASS){
        #pragma unroll
        for(int r=0;r<4;r++){
            float l = lsum[r];
            l += __shfl_xor(l,1); l += __shfl_xor(l,2);
            l += __shfl_xor(l,4); l += __shfl_xor(l,8);
            inv[r] = 1.f/l;
        }
    }
    __syncthreads();
    #pragma unroll
    for(int ni=0;ni<4;ni++){
        #pragma unroll
        for(int r=0;r<4;r++){
            int q = qb*64 + wm + rgrp*4 + r;
            int d = ni*16 + cidx;
            float o = acc_o[ni][r];
            if(ONEPASS) o *= inv[r];
            Og[((size_t)b*4096 + q)*256 + h*64 + d] = f2bf(o);
        }
    }
    if(IMP){
        size_t base = ((size_t)((b*4+h)*64) + qb)*976;
        for(int k=tid; k<NT*64 && k<976; k+=256)
            impp[base+k] = colacc[k];
    }
}

// ------------- deterministic importance reduce (256 rows/b) ------------------
__global__ void k_imp_reduce(const float* __restrict__ impp, float* __restrict__ imp){
    __shared__ float part[4][64];
    int b = blockIdx.y;
    int k = blockIdx.x*64 + (threadIdx.x & 63);
    int rr = threadIdx.x >> 6;
    float s = 0.f;
    if(k < 976){
        for(int r=rr; r<256; r+=4)
            s += impp[((size_t)(b*256) + r)*976 + k];
    }
    part[rr][threadIdx.x & 63] = s;
    __syncthreads();
    if(threadIdx.x < 64 && k < 961){
        float t = ((part[0][threadIdx.x] + part[1][threadIdx.x])
                 + part[2][threadIdx.x]) + part[3][threadIdx.x];
        imp[b*961 + k] = t;
    }
}

// ------------- top-16, parallel argmax, lowest-index tie-break ---------------
__global__ __launch_bounds__(256) void k_topk(const float* __restrict__ imp,
                                              int* __restrict__ idx){
    int b = blockIdx.x;
    __shared__ float v[961];
    __shared__ float wvv[4];
    __shared__ int   wvi[4];
    int t = threadIdx.x;
    int lane = t & 63, wid = t >> 6;
    for(int i=t;i<961;i+=256) v[i] = imp[b*961+i];
    __syncthreads();
    for(int it=0; it<16; it++){
        float bv = -1e30f; int bi = 1<<30;
        for(int i=t;i<961;i+=256){
            float val = v[i];
            if(val > bv){ bv=val; bi=i; }
        }
        #pragma unroll
        for(int off=32; off>0; off>>=1){
            float ov = __shfl_xor(bv, off);
            int   oi = __shfl_xor(bi, off);
            if(ov > bv || (ov == bv && oi < bi)){ bv = ov; bi = oi; }
        }
        if(lane==0){ wvv[wid]=bv; wvi[wid]=bi; }
        __syncthreads();
        if(t==0){
            float gb=wvv[0]; int gi=wvi[0];
            #pragma unroll
            for(int w=1;w<4;w++){
                if(wvv[w]>gb || (wvv[w]==gb && wvi[w]<gi)){ gb=wvv[w]; gi=wvi[w]; }
            }
            idx[b*16+it] = gi;
            v[gi] = -1e30f;
        }
        __syncthreads();
    }
}

// ------------- gather selected K/V (quirk layout, clip to 255) ----------------
__global__ void k_gather_sel(const float* __restrict__ qkv2, const int* __restrict__ idx,
                             u16* __restrict__ Ks, float* __restrict__ Vs){
    int row = blockIdx.x;            // b*256 + t ; t = sel*16 + p
    int b = row >> 8, tt = row & 255;
    int sel = tt >> 4, p = tt & 15;
    int blk = idx[b*16+sel]; if(blk > 255) blk = 255;
    int bi = blk >> 4, bj = blk & 15;
    int cc = threadIdx.x;
    int y = bi*4 + ((cc>>2)&3), xx = bj*4 + (cc&3);
    int ch = p*16 + (cc>>4);
    size_t src = ((size_t)(b*4096) + y*64 + xx)*768;
    Ks[(size_t)row*256 + cc] = f2bf(qkv2[src + 256 + ch]);
    Vs[(size_t)row*256 + cc] = qkv2[src + 512 + ch];
}

// ------------- build padded window tokens xw (bf16) --------------------------
__global__ void k_xw(const u16* __restrict__ xh, u16* __restrict__ xw){
    int row = blockIdx.x;             // wb*49 + t
    int wb = row / 49, t = row % 49;
    int b = wb / 100, wrem = wb % 100;
    int wy = wrem / 10, wx = wrem % 10;
    int ty = t / 7, tx = t % 7;
    int y = wy*7 + ty, xx = wx*7 + tx;
    int c = threadIdx.x;
    u16 v = 0;
    if(y < 64 && xx < 64) v = xh[((size_t)(b*4096) + y*64 + xx)*256 + c];
    xw[(size_t)row*256 + c] = v;
}

// ------------- window attention: 49 tokens, rel-pos bias; bf16 in/out --------
__global__ __launch_bounds__(64) void k_attn_win(
    const u16* __restrict__ qkvw, const float* __restrict__ btab,
    u16* __restrict__ outp)
{
    const int wb = blockIdx.x, h = blockIdx.y;
    const int lane = threadIdx.x;
    __shared__ float lk[49][64];
    __shared__ float lv[49][64];
    __shared__ float ls[49][51];
    __shared__ float lbias[169];
    for(int i=lane;i<169;i+=64) lbias[i] = btab[i*4 + h];
    for(int r=0;r<49;r++){
        lk[r][lane] = bf2f(qkvw[((size_t)(wb*49 + r))*768 + 256 + h*64 + lane]);
        lv[r][lane] = bf2f(qkvw[((size_t)(wb*49 + r))*768 + 512 + h*64 + lane]);
    }
    __syncthreads();
    if(lane < 49){
        const u16* qptr = &qkvw[((size_t)(wb*49 + lane))*768 + h*64];
        float qreg[64];
        #pragma unroll
        for(int d=0;d<64;++d) qreg[d] = bf2f(qptr[d]);
        int ih = lane/7, iw = lane%7;
        float m = -1e30f;
        for(int j=0;j<49;j++){
            float s0=0,s1=0,s2=0,s3=0;
            #pragma unroll
            for(int d=0; d<64; d+=4){
                s0 = fmaf(qreg[d+0], lk[j][d+0], s0);
                s1 = fmaf(qreg[d+1], lk[j][d+1], s1);
                s2 = fmaf(qreg[d+2], lk[j][d+2], s2);
                s3 = fmaf(qreg[d+3], lk[j][d+3], s3);
            }
            int jh=j/7, jw=j%7;
            float s = ((s0+s1)+(s2+s3))*0.125f + lbias[(ih-jh+6)*13 + (iw-jw+6)];
            ls[lane][j] = s;
            m = fmaxf(m, s);
        }
        float l = 0.f;
        for(int j=0;j<49;j++){ float p = __expf(ls[lane][j] - m); ls[lane][j] = p; l += p; }
        float inv = 1.f/l;
        u16* op = &outp[((size_t)(wb*49 + lane))*256 + h*64];
        for(int d=0;d<64;d++){
            float a0=0,a1=0;
            for(int j=0;j<48;j+=2){
                a0 = fmaf(ls[lane][j],   lv[j][d],   a0);
                a1 = fmaf(ls[lane][j+1], lv[j+1][d], a1);
            }
            a0 = fmaf(ls[lane][48], lv[48][d], a0);
            op[d] = f2bf((a0+a1)*inv);
        }
    }
}

// ------------- final gated combine + transpose to (B,C,H,W) f32 -------------
__global__ void k_combine(const float* __restrict__ ocp, const float* __restrict__ osp,
                          const float* __restrict__ owp, const float* __restrict__ g,
                          float* __restrict__ out){
    __shared__ float tile[32][33];
    int b = blockIdx.z; int c0 = blockIdx.y*32, n0 = blockIdx.x*32;
    int tx = threadIdx.x, ty = threadIdx.y;    // (32,8)
    for(int i=ty;i<32;i+=8){
        int n = n0 + i;
        float g0 = g[(size_t)(b*4096+n)*3 + 0];
        float g1 = g[(size_t)(b*4096+n)*3 + 1];
        float g2 = g[(size_t)(b*4096+n)*3 + 2];
        int y = n >> 6, xx = n & 63;
        int wy = y/7, ty2 = y%7, wx = xx/7, tx2 = xx%7;
        size_t wrow = (size_t)(b*100 + wy*10 + wx)*49 + ty2*7 + tx2;
        size_t base = ((size_t)(b*4096) + n)*256 + c0;
        float vc = ocp[base + tx];
        float vs = osp[base + tx];
        float vw = owp[wrow*256 + c0 + tx];
        tile[i][tx] = g0*vc + g1*vs + g2*vw;
    }
    __syncthreads();
    for(int i=ty;i<32;i+=8)
        out[((size_t)(b*256 + c0+i))*4096 + n0 + tx] = tile[tx][i];
}

// =============================== host side ===================================
extern "C" void kernel_launch(void* const* d_in, const int* in_sizes, int n_in,
                              void* d_out, int out_size, void* d_ws, size_t ws_size,
                              hipStream_t stream)
{
    typedef const float* fp;
    fp x          = (fp)d_in[0];
    fp qkv_cmp_w  = (fp)d_in[1];  fp qkv_cmp_b = (fp)d_in[2];
    fp qkv_slc_w  = (fp)d_in[3];  fp qkv_slc_b = (fp)d_in[4];
    fp cmpk_w1    = (fp)d_in[5];  fp cmpk_b1   = (fp)d_in[6];
    fp cmpk_w2    = (fp)d_in[7];  fp cmpk_b2   = (fp)d_in[8];
    fp cmpv_w1    = (fp)d_in[9];  fp cmpv_b1   = (fp)d_in[10];
    fp cmpv_w2    = (fp)d_in[11]; fp cmpv_b2   = (fp)d_in[12];
    fp pos_embed  = (fp)d_in[13];
    fp win_qkv_w  = (fp)d_in[14]; fp win_qkv_b = (fp)d_in[15];
    fp win_proj_w = (fp)d_in[16]; fp win_proj_b= (fp)d_in[17];
    fp win_btab   = (fp)d_in[18];
    fp proj_cmp_w = (fp)d_in[19]; fp proj_cmp_b= (fp)d_in[20];
    fp proj_slc_w = (fp)d_in[21]; fp proj_slc_b= (fp)d_in[22];
    fp gate_w1    = (fp)d_in[23]; fp gate_b1   = (fp)d_in[24];
    fp gate_w2    = (fp)d_in[25]; fp gate_b2   = (fp)d_in[26];
    (void)in_sizes; (void)n_in; (void)out_size;

    char* ws = (char*)d_ws;
    size_t off = 0;
    auto alloc = [&](size_t bytes)->size_t{
        size_t r = off; off += (bytes + 255) & ~(size_t)255; return r;
    };
    const size_t XSH  = alloc((size_t)16384*256*2);
    const size_t XSL  = alloc((size_t)16384*256*2);
    const size_t QKV  = alloc((size_t)16384*768*4);
    const size_t BIGA = alloc((size_t)4*4096*976*4);   // qkvw / out_win / out_slc
    const size_t HID  = alloc((size_t)3844*512*4);
    const size_t KCH  = alloc((size_t)3844*256*2);
    const size_t KCL  = alloc((size_t)3844*256*2);
    const size_t VC   = alloc((size_t)3844*256*4);
    const size_t S_IMPP = (size_t)4096*976*4;
    const size_t S_OC   = (size_t)16384*256*4;
    const size_t S_PB   = (size_t)4*4096*976*2;
    const size_t POOL = alloc(S_IMPP + S_OC + S_OC + S_PB);
    const size_t IMP  = alloc((size_t)4*961*4);
    const size_t IDX  = alloc((size_t)4*16*4);
    const size_t KS   = alloc((size_t)4*256*256*2);
    const size_t VS   = alloc((size_t)4*256*256*4);
    const size_t G2   = alloc((size_t)16384*3*4);
    const size_t VTC  = alloc((size_t)4*256*976*2);
    const size_t VTS  = alloc((size_t)4*256*256*2);
    const size_t POSB = alloc((size_t)512*4);
    const size_t POSP = alloc((size_t)64*512*4);
    const size_t TQS  = alloc((size_t)768*256*2);
    const size_t TWQ  = alloc((size_t)768*256*2);
    const size_t TV1  = alloc((size_t)512*4096*2);
    const size_t TV2  = alloc((size_t)256*512*2);
    const size_t TPC  = alloc((size_t)256*256*2);
    const size_t TPS  = alloc((size_t)256*256*2);
    const size_t TWP  = alloc((size_t)256*256*2);
    const size_t TG1  = alloc((size_t)64*256*2);
    const size_t TQCH = alloc((size_t)768*256*2);
    const size_t TQCL = alloc((size_t)768*256*2);
    const size_t TK1H = alloc((size_t)512*4096*2);
    const size_t TK1L = alloc((size_t)512*4096*2);
    const size_t TK2H = alloc((size_t)256*512*2);
    const size_t TK2L = alloc((size_t)256*512*2);
    if(off > ws_size) return;   // ~247 MB (budget proven)

    u16*   p_xsh = (u16*)(ws + XSH);
    u16*   p_xsl = (u16*)(ws + XSL);
    float* p_qkv = (float*)(ws + QKV);
    u16*   p_bigb= (u16*)  (ws + BIGA);
    float* p_oslc= (float*)(ws + BIGA);
    float* p_owp = (float*)(ws + BIGA + 20971520);
    float* p_hid = (float*)(ws + HID);
    u16*   p_kch = (u16*)(ws + KCH);
    u16*   p_kcl = (u16*)(ws + KCL);
    float* p_vc  = (float*)(ws + VC);
    float* p_impp= (float*)(ws + POOL);
    u16*   p_oc16= (u16*)  (ws + POOL + S_IMPP);
    float* p_ocp = (float*)(ws + POOL + S_IMPP + S_OC);
    u16*   p_kfh = (u16*)  (ws + POOL);
    u16*   p_kfl = p_kfh + (size_t)4*4096*256;
    u16*   p_vf  = p_kfl + (size_t)4*4096*256;
    u16*   p_xwb = (u16*)  (ws + POOL);
    u16*   p_owin= (u16*)  (ws + POOL + S_IMPP);
    float* p_imp = (float*)(ws + IMP);
    int*   p_idx = (int*)  (ws + IDX);
    u16*   p_ks  = (u16*)(ws + KS);
    float* p_vs  = (float*)(ws + VS);
    float* p_g   = (float*)(ws + G2);
    u16*   p_vtc = (u16*)(ws + VTC);
    u16*   p_vts = (u16*)(ws + VTS);
    float* p_posb= (float*)(ws + POSB);
    float* p_posp= (float*)(ws + POSP);
    u16* t_qs = (u16*)(ws + TQS);
    u16* t_wq = (u16*)(ws + TWQ);
    u16* t_v1 = (u16*)(ws + TV1);
    u16* t_v2 = (u16*)(ws + TV2);
    u16* t_pc = (u16*)(ws + TPC);
    u16* t_ps = (u16*)(ws + TPS);
    u16* t_wp = (u16*)(ws + TWP);
    u16* t_g1 = (u16*)(ws + TG1);
    u16* t_qch= (u16*)(ws + TQCH);
    u16* t_qcl= (u16*)(ws + TQCL);
    u16* t_k1h= (u16*)(ws + TK1H);
    u16* t_k1l= (u16*)(ws + TK1L);
    u16* t_k2h= (u16*)(ws + TK2H);
    u16* t_k2l= (u16*)(ws + TK2L);

    auto wt = [&](fp W, u16* WT, int K, int Nn, int perm){
        k_wt<<<dim3((K+31)/32, (Nn+31)/32), dim3(32,8), 0, stream>>>(W, WT, K, Nn, perm);
    };
    auto wt2 = [&](fp W, u16* H, u16* L, int K, int Nn, int perm){
        k_wt2<<<dim3((K+31)/32, (Nn+31)/32), dim3(32,8), 0, stream>>>(W, H, L, K, Nn, perm);
    };

    // 0. weight preprocessing (w1 matrices K-permuted for implicit unfold)
    wt(qkv_slc_w, t_qs, 256, 768, 0);
    wt(win_qkv_w, t_wq, 256, 768, 0);
    wt(cmpv_w1,   t_v1, 4096, 512, 1);
    wt(cmpv_w2,   t_v2, 512, 256, 0);
    wt(proj_cmp_w,t_pc, 256, 256, 0);
    wt(proj_slc_w,t_ps, 256, 256, 0);
    wt(win_proj_w,t_wp, 256, 256, 0);
    wt(gate_w1,   t_g1, 256, 64, 0);
    wt2(qkv_cmp_w, t_qch, t_qcl, 256, 768, 0);
    wt2(cmpk_w1,   t_k1h, t_k1l, 4096, 512, 1);
    wt2(cmpk_w2,   t_k2h, t_k2l, 512, 256, 0);
    k_posw1a<<<dim3(8,64), 256, 0, stream>>>(pos_embed, cmpk_w1, p_posp);
    k_posw1b<<<2, 256, 0, stream>>>(p_posp, cmpk_b1, p_posb);

    // 1. xs (bf16 hi/lo)
    k_xs<<<dim3(128,8,4), dim3(32,8), 0, stream>>>(x, p_xsh, p_xsl);
    // 2. qkv_cmp (split, A pair, B pair)
    k_mgs<4,4,2,2,3,0><<<dim3(6,128), 256, 0, stream>>>(
        nullptr, p_xsh, p_xsl, nullptr, t_qch, t_qcl, qkv_cmp_b, p_qkv, nullptr, nullptr,
        16384, 768, 256, 256, 256, 768, 0, 1.0f, 0, 0, 0);
    // 3. channel split: K field pair + V field (POOL alias)
    k_splitkv<<<dim3(4096,4), 256, 0, stream>>>(p_qkv, p_kfh, p_kfl, p_vf);
    // 4-5. compressed K path (implicit-unfold split GEMM; pos folded in bias)
    k_mgs_unf<1><<<dim3(8,61), 256, 0, stream>>>(
        p_kfh, p_kfl, t_k1h, t_k1l, p_posb, p_hid);
    k_mgs<2,2,0,2,3,2><<<dim3(4,61), 256, 0, stream>>>(
        p_hid, nullptr, nullptr, nullptr, t_k2h, t_k2l, cmpk_b2, nullptr, p_kch, p_kcl,
        3844, 256, 512, 512, 512, 256, 0, 1.0f, 0, 0, 0);
    // 6-7. compressed V path (implicit-unfold single GEMM)
    k_mgs_unf<0><<<dim3(8,61), 256, 0, stream>>>(
        p_vf, nullptr, t_v1, nullptr, cmpv_b1, p_hid);
    k_mgs<2,2,0,1,1,0><<<dim3(4,61), 256, 0, stream>>>(
        p_hid, nullptr, nullptr, nullptr, t_v2, nullptr, cmpv_b2, p_vc, nullptr, nullptr,
        3844, 256, 512, 512, 512, 256, 0, 1.0f, 0, 0, 0);
    // V^T bf16 (zero-padded to 976)
    k_vt<<<dim3(31,8,4), dim3(32,8), 0, stream>>>(p_vc, p_vtc, 961, 976);
    // 9. compressed attention — fused flash (2-pass, importance), bf16 O
    k_fattn<1,1,0,961,16,976><<<dim3(64,4,4), 256, 0, stream>>>(
        p_qkv, p_kch, p_kcl, p_vtc, p_oc16, p_impp);
    k_imp_reduce<<<dim3(16,4), 256, 0, stream>>>(p_impp, p_imp);
    k_topk<<<4, 256, 0, stream>>>(p_imp, p_idx);
    // 10. out_cmp projection (bf16 A)
    k_mgs<4,4,1,1,1,0><<<dim3(2,128), 256, 0, stream>>>(
        nullptr, p_oc16, nullptr, nullptr, t_pc, nullptr, proj_cmp_b, p_ocp, nullptr, nullptr,
        16384, 256, 256, 256, 256, 256, 0, 1.0f, 0, 0, 0);
    // 11. qkv_slc (A = xs hi bf16)
    k_mgs<4,4,1,1,1,0><<<dim3(6,128), 256, 0, stream>>>(
        nullptr, p_xsh, nullptr, nullptr, t_qs, nullptr, qkv_slc_b, p_qkv, nullptr, nullptr,
        16384, 768, 256, 256, 256, 768, 0, 1.0f, 0, 0, 0);
    // 12-14. window branch
    k_xw<<<19600, 256, 0, stream>>>(p_xsh, p_xwb);
    k_mgs<4,4,1,1,1,1><<<dim3(6,154), 256, 0, stream>>>(
        nullptr, p_xwb, nullptr, nullptr, t_wq, nullptr, win_qkv_b, nullptr, p_bigb, nullptr,
        19600, 768, 256, 256, 256, 768, 0, 1.0f, 0, 0, 0);
    k_attn_win<<<dim3(400,4), 64, 0, stream>>>(p_bigb, win_btab, p_owin);
    k_mgs<4,4,1,1,1,0><<<dim3(2,154), 256, 0, stream>>>(
        nullptr, p_owin, nullptr, nullptr, t_wp, nullptr, win_proj_b, p_owp, nullptr, nullptr,
        19600, 256, 256, 256, 256, 256, 0, 1.0f, 0, 0, 0);
    // 15-16. selected branch — single-pass fused flash, bf16 O
    k_gather_sel<<<1024, 256, 0, stream>>>(p_qkv, p_idx, p_ks, p_vs);
    k_vt<<<dim3(8,8,4), dim3(32,8), 0, stream>>>(p_vs, p_vts, 256, 256);
    k_fattn<0,0,1,256,4,256><<<dim3(64,4,4), 256, 0, stream>>>(
        p_qkv, p_ks, nullptr, p_vts, p_oc16, nullptr);
    // 17. out_slc projection (bf16 A)
    k_mgs<4,4,1,1,1,0><<<dim3(2,128), 256, 0, stream>>>(
        nullptr, p_oc16, nullptr, nullptr, t_ps, nullptr, proj_slc_b, p_oslc, nullptr, nullptr,
        16384, 256, 256, 256, 256, 256, 0, 1.0f, 0, 0, 0);
    // 18-19. gate
    k_mgs<2,2,1,1,1,0><<<dim3(1,256), 256, 0, stream>>>(
        nullptr, p_xsh, nullptr, nullptr, t_g1, nullptr, gate_b1, p_hid, nullptr, nullptr,
        16384, 64, 256, 256, 256, 64, 1, 1.0f, 0, 0, 0);
    k_gemm<<<dim3(1,256), 256, 0, stream>>>(p_hid, gate_w2, gate_b2, p_g,
                                            16384, 64, 3, 2);
    // 20. combine
    k_combine<<<dim3(128,8,4), dim3(32,8), 0, stream>>>(p_ocp, p_oslc, p_owp, p_g,
                                                        (float*)d_out);
}